// Round 6
// baseline (1684.642 us; speedup 1.0000x reference)
//
#include <hip/hip_runtime.h>

// B=32768, K=16, D=256, H=2, HD=128
#define Bsz 32768
#define BR  16           // rows per block (4 per wave)
#define SCALE 0.08838834764831845f   // 1/sqrt(128)

typedef __attribute__((ext_vector_type(4))) float f32x4;
typedef __attribute__((ext_vector_type(4))) unsigned short us4;

static __device__ __forceinline__ unsigned short f2bf(float x){
  unsigned int u = __builtin_bit_cast(unsigned int, x);
  u += 0x7FFFu + ((u >> 16) & 1u);          // RNE
  return (unsigned short)(u >> 16);
}
static __device__ __forceinline__ float bf2f(unsigned short h){
  unsigned int u = ((unsigned int)h) << 16;
  return __builtin_bit_cast(float, u);
}

// ---------------------------------------------------------------------------
// Prep (identical to passing round 5): fp32 weights, k-major.
//   W1T f32 [256][640]: n<512 -> M_h[k][m]; n in 512..639 -> Wc
//   W2T f32 [256][256]: Wv transposed;  W3T f32 [256][128]: Wx transposed
// ---------------------------------------------------------------------------
__global__ void prep_kernel(const float* __restrict__ Wq, const float* __restrict__ Wk,
                            const float* __restrict__ Wv, const float* __restrict__ Wc,
                            const float* __restrict__ Wx, float* __restrict__ wsf){
  float* W1T = wsf;                  // [256][640]
  float* W2T = wsf + 256*640;        // [256][256]
  float* W3T = W2T + 256*256;        // [256][128]
  const int n = blockIdx.x;
  const int k = threadIdx.x;
  if (n < 512){
    const int h = n >> 8, m = n & 255;
    const float* wq = Wq + h*128*256 + k;
    const float* wk = Wk + h*128*256 + m;
    float s = 0.f;
    for (int d = 0; d < 128; ++d) s += wq[d*256] * wk[d*256];
    W1T[k*640 + n] = s;
  } else if (n < 640){
    W1T[k*640 + n] = Wc[(n-512)*256 + k];
  } else if (n < 896){
    const int r = n - 640;
    W2T[k*256 + r] = Wv[r*256 + k];
  } else {
    const int r = n - 896;
    W3T[k*128 + r] = Wx[r*256 + k];
  }
}

// ---------------------------------------------------------------------------
// Fused kernel. 16 rows/block, 256 threads. All cross-lane traffic is
// wave-local (rows 4w..4w+3 belong to wave w in every phase); barriers only
// order LDS handoffs.
// LDS (33.5 KB -> 4 blocks/CU):
//   s_c    f32 [16][260]: center (stage..A); then bf16 agg [16][520] (B..C);
//                         then bf16 ctx_n [16][<520] (D..E)   (overlays)
//   s_ctil bf16[16][528]: ctil (A..B)
// Phase C accumulates ctx in registers; LayerNorm reduces via 16-lane-group
// shfl_xor (threads (tr,0..15) share a row and a shuffle nibble-group).
// ---------------------------------------------------------------------------
__global__ __launch_bounds__(256, 4) void fused_kernel(
    const float* __restrict__ center, const float* __restrict__ nbr,
    const float* __restrict__ ew, const float* __restrict__ gamma,
    const float* __restrict__ beta, const float* __restrict__ Wall,
    float* __restrict__ out)
{
  __shared__ __align__(16) float s_c[BR*260];
  __shared__ __align__(16) unsigned short s_ctil[BR*528];
  unsigned short* s_ag = (unsigned short*)s_c;   // bf16 overlay, row stride 520

  const int tid  = threadIdx.x;
  const int wid  = tid >> 6;
  const int lane = tid & 63;
  const int b0   = blockIdx.x * BR;

  const float* W1T = Wall;               // [256][640]
  const float* W2T = Wall + 256*640;     // [256][256]
  const float* W3T = W2T + 256*256;      // [256][128]

  const int tr = tid >> 4;     // 0..15 (row owned in GEMM-ish phases)
  const int tc = tid & 15;     // 0..15

  // ---- stage center tile -> fp32 LDS ----
  {
    const float* cp = center + ((long)(b0 + tr) << 8) + tc*16;
    #pragma unroll
    for (int it = 0; it < 4; ++it)
      *(float4*)&s_c[tr*260 + tc*16 + it*4] = *(const float4*)(cp + it*4);
  }
  __syncthreads();

  // ---- Phase A: [16x256]@[256x640] -> ctil bf16 (LDS) + out-left (global) ----
  {
    f32x4 acc[10];
    #pragma unroll
    for (int t = 0; t < 10; ++t) acc[t] = (f32x4){0.f,0.f,0.f,0.f};
    #pragma unroll 2
    for (int k = 0; k < 256; ++k){
      const float a = s_c[tr*260 + k];
      const f32x4* w = (const f32x4*)(W1T + k*640) + tc;
      #pragma unroll
      for (int t = 0; t < 10; ++t)
        acc[t] += a * w[t*16];
    }
    #pragma unroll
    for (int t = 0; t < 8; ++t){
      us4 v;
      v[0]=f2bf(acc[t][0]); v[1]=f2bf(acc[t][1]);
      v[2]=f2bf(acc[t][2]); v[3]=f2bf(acc[t][3]);
      *(us4*)&s_ctil[tr*528 + t*64 + tc*4] = v;
    }
    float* op = out + ((long)(b0 + tr) << 8) + tc*4;
    *(f32x4*)(op)      = acc[8];    // out cols 0..63
    *(f32x4*)(op + 64) = acc[9];    // out cols 64..127
  }
  __syncthreads();

  // ---- Phase B: attention; agg -> bf16 overlay of s_c ----
  {
    #pragma unroll 1
    for (int rr = 0; rr < 4; ++rr){
      const int r = wid*4 + rr;
      const long b = b0 + r;
      float4 c0, c1;
      {
        us4 h0 = *(const us4*)&s_ctil[r*528 + lane*4];
        us4 h1 = *(const us4*)&s_ctil[r*528 + 256 + lane*4];
        c0.x=bf2f(h0[0]); c0.y=bf2f(h0[1]); c0.z=bf2f(h0[2]); c0.w=bf2f(h0[3]);
        c1.x=bf2f(h1[0]); c1.y=bf2f(h1[1]); c1.z=bf2f(h1[2]); c1.w=bf2f(h1[3]);
      }
      const float4* ewp = (const float4*)(ew + b*16);
      float er[16];
      #pragma unroll
      for (int j = 0; j < 4; ++j){
        float4 e = ewp[j];
        er[4*j]=e.x; er[4*j+1]=e.y; er[4*j+2]=e.z; er[4*j+3]=e.w;
      }
      const float* npt = nbr + ((b << 4) << 8) + lane*4;
      float sum0 = 0.f, sum1 = 0.f;
      float4 agg0 = {0,0,0,0}, agg1 = {0,0,0,0};
      #pragma unroll 1
      for (int half = 0; half < 2; ++half){
        float4 xv[8];
        #pragma unroll
        for (int k = 0; k < 8; ++k) xv[k] = *(const float4*)(npt + ((half*8 + k) << 8));
        #pragma unroll
        for (int k = 0; k < 8; ++k){
          float p0 = xv[k].x*c0.x + xv[k].y*c0.y + xv[k].z*c0.z + xv[k].w*c0.w;
          float p1 = xv[k].x*c1.x + xv[k].y*c1.y + xv[k].z*c1.z + xv[k].w*c1.w;
          #pragma unroll
          for (int m = 32; m >= 1; m >>= 1){
            p0 += __shfl_xor(p0, m, 64);
            p1 += __shfl_xor(p1, m, 64);
          }
          const float w0 = __expf(p0*SCALE + er[half*8 + k]);  // scores O(1): no max-sub
          const float w1 = __expf(p1*SCALE + er[half*8 + k]);
          sum0 += w0; sum1 += w1;
          agg0.x += w0*xv[k].x; agg0.y += w0*xv[k].y; agg0.z += w0*xv[k].z; agg0.w += w0*xv[k].w;
          agg1.x += w1*xv[k].x; agg1.y += w1*xv[k].y; agg1.z += w1*xv[k].z; agg1.w += w1*xv[k].w;
        }
      }
      const float i0 = 1.0f / sum0, i1 = 1.0f / sum1;
      us4 v0, v1;
      v0[0]=f2bf(agg0.x*i0); v0[1]=f2bf(agg0.y*i0); v0[2]=f2bf(agg0.z*i0); v0[3]=f2bf(agg0.w*i0);
      v1[0]=f2bf(agg1.x*i1); v1[1]=f2bf(agg1.y*i1); v1[2]=f2bf(agg1.z*i1); v1[3]=f2bf(agg1.w*i1);
      *(us4*)&s_ag[r*520 + lane*4]       = v0;   // head-0 agg (overlays dead center)
      *(us4*)&s_ag[r*520 + 256 + lane*4] = v1;   // head-1 agg
    }
  }
  __syncthreads();

  // ---- Phase C: ctx (registers) = agg_h @ Wv_h^T, coalesced k-major ----
  f32x4 ac0 = {0,0,0,0}, ac1 = {0,0,0,0}, ac2 = {0,0,0,0}, ac3 = {0,0,0,0};
  {
    #pragma unroll 2
    for (int k = 0; k < 256; ++k){
      const float a0 = bf2f(s_ag[tr*520 + k]);
      const float a1 = bf2f(s_ag[tr*520 + 256 + k]);
      const f32x4* w = (const f32x4*)(W2T + (k << 8)) + tc;
      ac0 += a0 * w[0];       // cols   0.. 63 (head 0)
      ac1 += a0 * w[16];      // cols  64..127 (head 0)
      ac2 += a1 * w[32];      // cols 128..191 (head 1)
      ac3 += a1 * w[48];      // cols 192..255 (head 1)
    }
  }
  __syncthreads();

  // ---- Phase D: LayerNorm in registers (16-lane-group reduce), ctx_n -> bf16 LDS ----
  {
    float s = 0.f, q = 0.f;
    #pragma unroll
    for (int j = 0; j < 4; ++j){
      s += ac0[j] + ac1[j] + ac2[j] + ac3[j];
      q += ac0[j]*ac0[j] + ac1[j]*ac1[j] + ac2[j]*ac2[j] + ac3[j]*ac3[j];
    }
    #pragma unroll
    for (int m = 8; m >= 1; m >>= 1){      // reduce across tc (low nibble)
      s += __shfl_xor(s, m, 64);
      q += __shfl_xor(q, m, 64);
    }
    const float mu  = s * (1.f/256.f);
    const float var = q * (1.f/256.f) - mu*mu;
    const float rs  = rsqrtf(var + 1e-5f);
    const f32x4* gp = (const f32x4*)gamma + tc;
    const f32x4* bp = (const f32x4*)beta  + tc;
    f32x4 accs[4] = {ac0, ac1, ac2, ac3};
    #pragma unroll
    for (int t = 0; t < 4; ++t){
      f32x4 g = gp[t*16];
      f32x4 bb = bp[t*16];
      us4 v;
      #pragma unroll
      for (int j = 0; j < 4; ++j)
        v[j] = f2bf((accs[t][j] - mu)*rs*g[j] + bb[j]);
      *(us4*)&s_ag[tr*520 + t*64 + tc*4] = v;    // ctx_n bf16, cols t*64+tc*4
    }
  }
  __syncthreads();

  // ---- Phase E: out-right[16x128] = ctx_n @ Wx^T, coalesced k-major ----
  {
    f32x4 e0 = {0,0,0,0}, e1 = {0,0,0,0};
    #pragma unroll 2
    for (int k = 0; k < 256; ++k){
      const float a = bf2f(s_ag[tr*520 + k]);
      const f32x4* w = (const f32x4*)(W3T + (k << 7)) + tc;
      e0 += a * w[0];         // out cols 128..191
      e1 += a * w[16];        // out cols 192..255
    }
    float* op = out + ((long)(b0 + tr) << 8) + 128 + tc*4;
    *(f32x4*)(op)      = e0;
    *(f32x4*)(op + 64) = e1;
  }
}

extern "C" void kernel_launch(void* const* d_in, const int* in_sizes, int n_in,
                              void* d_out, int out_size, void* d_ws, size_t ws_size,
                              hipStream_t stream){
  const float* center = (const float*)d_in[0];
  const float* nbr    = (const float*)d_in[1];
  const float* ew     = (const float*)d_in[2];
  const float* Wq     = (const float*)d_in[3];
  const float* Wk     = (const float*)d_in[4];
  const float* Wv     = (const float*)d_in[5];
  const float* Wc     = (const float*)d_in[6];
  const float* Wx     = (const float*)d_in[7];
  const float* gamma  = (const float*)d_in[8];
  const float* beta   = (const float*)d_in[9];
  (void)in_sizes; (void)n_in; (void)out_size;

  float* W = (float*)d_ws;   // exactly 1 MiB of workspace
  (void)ws_size;

  prep_kernel<<<1024, 256, 0, stream>>>(Wq, Wk, Wv, Wc, Wx, W);
  fused_kernel<<<Bsz/BR, 256, 0, stream>>>(center, nbr, ew, gamma, beta, W, (float*)d_out);
}

// Round 7
// 1684.229 us; speedup vs baseline: 1.0002x; 1.0002x over previous
//
#include <hip/hip_runtime.h>

// B=32768, K=16, D=256, H=2, HD=128
#define Bsz 32768
#define BR  32           // rows per block (8 per wave; 2 per thread in A/C/E)
#define SCALE 0.08838834764831845f   // 1/sqrt(128)

typedef __attribute__((ext_vector_type(4))) float f32x4;
typedef __attribute__((ext_vector_type(4))) unsigned short us4;
typedef __attribute__((ext_vector_type(8))) unsigned short us8;

static __device__ __forceinline__ unsigned short f2bf(float x){
  unsigned int u = __builtin_bit_cast(unsigned int, x);
  u += 0x7FFFu + ((u >> 16) & 1u);          // RNE
  return (unsigned short)(u >> 16);
}
static __device__ __forceinline__ float bf2f(unsigned short h){
  unsigned int u = ((unsigned int)h) << 16;
  return __builtin_bit_cast(float, u);
}

// ---------------------------------------------------------------------------
// Prep (identical to passing rounds 5/6): fp32 weights, k-major.
//   W1T f32 [256][640]: n<512 -> M_h[k][m] (m=n&255,h=n>>8); n in 512..639 -> Wc
//   W2T f32 [256][256]: Wv transposed;  W3T f32 [256][128]: Wx transposed
// ---------------------------------------------------------------------------
__global__ void prep_kernel(const float* __restrict__ Wq, const float* __restrict__ Wk,
                            const float* __restrict__ Wv, const float* __restrict__ Wc,
                            const float* __restrict__ Wx, float* __restrict__ wsf){
  float* W1T = wsf;                  // [256][640]
  float* W2T = wsf + 256*640;        // [256][256]
  float* W3T = W2T + 256*256;        // [256][128]
  const int n = blockIdx.x;
  const int k = threadIdx.x;
  if (n < 512){
    const int h = n >> 8, m = n & 255;
    const float* wq = Wq + h*128*256 + k;
    const float* wk = Wk + h*128*256 + m;
    float s = 0.f;
    for (int d = 0; d < 128; ++d) s += wq[d*256] * wk[d*256];
    W1T[k*640 + n] = s;
  } else if (n < 640){
    W1T[k*640 + n] = Wc[(n-512)*256 + k];
  } else if (n < 896){
    const int r = n - 640;
    W2T[k*256 + r] = Wv[r*256 + k];
  } else {
    const int r = n - 896;
    W3T[k*128 + r] = Wx[r*256 + k];
  }
}

// ---------------------------------------------------------------------------
// Fused kernel, BR=32, 256 threads (4 waves).
// Thread (tg,tc)=(tid>>4, tid&15) owns rows {tg, tg+16}, cols {64t+4tc+j}.
// LDS (50.7 KB -> 3 blocks/CU):
//   s_cb  bf16 [32][264]: center (stage..A); ctx_n (D..E) overlay
//   s_ctil bf16 [32][528]: ctil cols 0..511 (A..B); agg (B..C) same-cell overlay
// Hazards: agg overlays ctil per-lane same-cell (same-wave WAR, safe);
// C->D->E are wave-local on the tg group; barriers: stage|A, A|B, B|C, D|E.
// ---------------------------------------------------------------------------
__global__ __launch_bounds__(256, 3) void fused_kernel(
    const float* __restrict__ center, const float* __restrict__ nbr,
    const float* __restrict__ ew, const float* __restrict__ gamma,
    const float* __restrict__ beta, const float* __restrict__ Wall,
    float* __restrict__ out)
{
  __shared__ __align__(16) unsigned short s_cb[BR*264];
  __shared__ __align__(16) unsigned short s_ctil[BR*528];

  const int tid  = threadIdx.x;
  const int wid  = tid >> 6;
  const int lane = tid & 63;
  const int b0   = blockIdx.x * BR;

  const float* W1T = Wall;               // [256][640]
  const float* W2T = Wall + 256*640;     // [256][256]
  const float* W3T = W2T + 256*256;      // [256][128]

  const int tg = tid >> 4;     // 0..15
  const int tc = tid & 15;     // 0..15
  const int r0 = tg;
  const int r1 = tg + 16;

  // ---- stage center -> bf16 LDS ----
  {
    const int sr = tid >> 3;            // 0..31
    const int sc = (tid & 7) * 32;      // 0..224
    const float* cp = center + ((long)(b0 + sr) << 8) + sc;
    #pragma unroll
    for (int it = 0; it < 4; ++it){
      float4 a = *(const float4*)(cp + it*8);
      float4 b = *(const float4*)(cp + it*8 + 4);
      us8 v;
      v[0]=f2bf(a.x); v[1]=f2bf(a.y); v[2]=f2bf(a.z); v[3]=f2bf(a.w);
      v[4]=f2bf(b.x); v[5]=f2bf(b.y); v[6]=f2bf(b.z); v[7]=f2bf(b.w);
      *(us8*)&s_cb[sr*264 + sc + it*8] = v;
    }
  }
  __syncthreads();

  // ---- Phase A: [32x256]@[256x640] -> ctil bf16 + out-left; 2 rows/thread ----
  {
    f32x4 acc0[10], acc1[10];
    #pragma unroll
    for (int t = 0; t < 10; ++t){ acc0[t] = (f32x4){0,0,0,0}; acc1[t] = (f32x4){0,0,0,0}; }
    #pragma unroll 2
    for (int k = 0; k < 256; ++k){
      const float a0 = bf2f(s_cb[r0*264 + k]);
      const float a1 = bf2f(s_cb[r1*264 + k]);
      const f32x4* w = (const f32x4*)(W1T + k*640) + tc;
      #pragma unroll
      for (int t = 0; t < 10; ++t){
        const f32x4 wv = w[t*16];
        acc0[t] += a0 * wv;
        acc1[t] += a1 * wv;
      }
    }
    #pragma unroll
    for (int t = 0; t < 8; ++t){
      us4 v0, v1;
      #pragma unroll
      for (int j = 0; j < 4; ++j){ v0[j] = f2bf(acc0[t][j]); v1[j] = f2bf(acc1[t][j]); }
      *(us4*)&s_ctil[r0*528 + t*64 + tc*4] = v0;
      *(us4*)&s_ctil[r1*528 + t*64 + tc*4] = v1;
    }
    float* op0 = out + ((long)(b0 + r0) << 8) + tc*4;
    float* op1 = out + ((long)(b0 + r1) << 8) + tc*4;
    *(f32x4*)(op0)      = acc0[8];
    *(f32x4*)(op0 + 64) = acc0[9];
    *(f32x4*)(op1)      = acc1[8];
    *(f32x4*)(op1 + 64) = acc1[9];
  }
  __syncthreads();

  // ---- Phase B: attention, 8 rows/wave; agg bf16 overlays own ctil cells ----
  {
    #pragma unroll 1
    for (int rr = 0; rr < 8; ++rr){
      const int r = wid*8 + rr;
      const long b = b0 + r;
      float4 c0, c1;
      {
        us4 h0 = *(const us4*)&s_ctil[r*528 + lane*4];
        us4 h1 = *(const us4*)&s_ctil[r*528 + 256 + lane*4];
        c0.x=bf2f(h0[0]); c0.y=bf2f(h0[1]); c0.z=bf2f(h0[2]); c0.w=bf2f(h0[3]);
        c1.x=bf2f(h1[0]); c1.y=bf2f(h1[1]); c1.z=bf2f(h1[2]); c1.w=bf2f(h1[3]);
      }
      const float4* ewp = (const float4*)(ew + b*16);
      float er[16];
      #pragma unroll
      for (int j = 0; j < 4; ++j){
        float4 e = ewp[j];
        er[4*j]=e.x; er[4*j+1]=e.y; er[4*j+2]=e.z; er[4*j+3]=e.w;
      }
      float4 xv[16];
      const float* npt = nbr + ((b << 4) << 8) + lane*4;
      #pragma unroll
      for (int k = 0; k < 16; ++k) xv[k] = *(const float4*)(npt + (k << 8));
      float sum0 = 0.f, sum1 = 0.f;
      float4 agg0 = {0,0,0,0}, agg1 = {0,0,0,0};
      #pragma unroll
      for (int k = 0; k < 16; ++k){
        float p0 = xv[k].x*c0.x + xv[k].y*c0.y + xv[k].z*c0.z + xv[k].w*c0.w;
        float p1 = xv[k].x*c1.x + xv[k].y*c1.y + xv[k].z*c1.z + xv[k].w*c1.w;
        #pragma unroll
        for (int m = 32; m >= 1; m >>= 1){
          p0 += __shfl_xor(p0, m, 64);
          p1 += __shfl_xor(p1, m, 64);
        }
        const float w0 = __expf(p0*SCALE + er[k]);   // scores O(1): no max-sub needed
        const float w1 = __expf(p1*SCALE + er[k]);
        sum0 += w0; sum1 += w1;
        agg0.x += w0*xv[k].x; agg0.y += w0*xv[k].y; agg0.z += w0*xv[k].z; agg0.w += w0*xv[k].w;
        agg1.x += w1*xv[k].x; agg1.y += w1*xv[k].y; agg1.z += w1*xv[k].z; agg1.w += w1*xv[k].w;
      }
      const float i0 = 1.0f / sum0, i1 = 1.0f / sum1;
      us4 v0, v1;
      v0[0]=f2bf(agg0.x*i0); v0[1]=f2bf(agg0.y*i0); v0[2]=f2bf(agg0.z*i0); v0[3]=f2bf(agg0.w*i0);
      v1[0]=f2bf(agg1.x*i1); v1[1]=f2bf(agg1.y*i1); v1[2]=f2bf(agg1.z*i1); v1[3]=f2bf(agg1.w*i1);
      *(us4*)&s_ctil[r*528 + lane*4]       = v0;   // same cells this lane read (WAR ok)
      *(us4*)&s_ctil[r*528 + 256 + lane*4] = v1;
    }
  }
  __syncthreads();

  // ---- Phase C: ctx (regs) = agg_h @ Wv_h^T; 2 rows/thread, coalesced ----
  f32x4 c00={0,0,0,0}, c01={0,0,0,0}, c02={0,0,0,0}, c03={0,0,0,0};
  f32x4 c10={0,0,0,0}, c11={0,0,0,0}, c12={0,0,0,0}, c13={0,0,0,0};
  {
    #pragma unroll 2
    for (int k = 0; k < 256; ++k){
      const float a00 = bf2f(s_ctil[r0*528 + k]);         // row r0 head0
      const float a01 = bf2f(s_ctil[r0*528 + 256 + k]);   // row r0 head1
      const float a10 = bf2f(s_ctil[r1*528 + k]);
      const float a11 = bf2f(s_ctil[r1*528 + 256 + k]);
      const f32x4* w = (const f32x4*)(W2T + (k << 8)) + tc;
      const f32x4 w0 = w[0], w1 = w[16], w2 = w[32], w3 = w[48];
      c00 += a00*w0; c01 += a00*w1; c02 += a01*w2; c03 += a01*w3;
      c10 += a10*w0; c11 += a10*w1; c12 += a11*w2; c13 += a11*w3;
    }
  }

  // ---- Phase D: LayerNorm in registers (16-lane reduce), ctx_n bf16 -> s_cb ----
  {
    f32x4 gv[4], bv[4];
    #pragma unroll
    for (int t = 0; t < 4; ++t){
      gv[t] = *((const f32x4*)gamma + t*16 + tc);
      bv[t] = *((const f32x4*)beta  + t*16 + tc);
    }
    f32x4 rowacc[2][4] = {{c00,c01,c02,c03},{c10,c11,c12,c13}};
    #pragma unroll
    for (int i = 0; i < 2; ++i){
      float s = 0.f, q = 0.f;
      #pragma unroll
      for (int t = 0; t < 4; ++t)
        #pragma unroll
        for (int j = 0; j < 4; ++j){
          const float x = rowacc[i][t][j];
          s += x; q += x*x;
        }
      #pragma unroll
      for (int m = 8; m >= 1; m >>= 1){
        s += __shfl_xor(s, m, 64);
        q += __shfl_xor(q, m, 64);
      }
      const float mu  = s * (1.f/256.f);
      const float var = q * (1.f/256.f) - mu*mu;
      const float rs  = rsqrtf(var + 1e-5f);
      const int r = (i == 0) ? r0 : r1;
      #pragma unroll
      for (int t = 0; t < 4; ++t){
        us4 v;
        #pragma unroll
        for (int j = 0; j < 4; ++j)
          v[j] = f2bf((rowacc[i][t][j] - mu)*rs*gv[t][j] + bv[t][j]);
        *(us4*)&s_cb[r*264 + t*64 + tc*4] = v;
      }
    }
  }
  __syncthreads();

  // ---- Phase E: out-right = ctx_n @ Wx^T; 2 rows/thread, coalesced ----
  {
    f32x4 e00={0,0,0,0}, e01={0,0,0,0}, e10={0,0,0,0}, e11={0,0,0,0};
    #pragma unroll 2
    for (int k = 0; k < 256; ++k){
      const float a0 = bf2f(s_cb[r0*264 + k]);
      const float a1 = bf2f(s_cb[r1*264 + k]);
      const f32x4* w = (const f32x4*)(W3T + (k << 7)) + tc;
      const f32x4 w0 = w[0], w1 = w[16];
      e00 += a0*w0; e01 += a0*w1;
      e10 += a1*w0; e11 += a1*w1;
    }
    float* op0 = out + ((long)(b0 + r0) << 8) + 128 + tc*4;
    float* op1 = out + ((long)(b0 + r1) << 8) + 128 + tc*4;
    *(f32x4*)(op0)      = e00;
    *(f32x4*)(op0 + 64) = e01;
    *(f32x4*)(op1)      = e10;
    *(f32x4*)(op1 + 64) = e11;
  }
}

extern "C" void kernel_launch(void* const* d_in, const int* in_sizes, int n_in,
                              void* d_out, int out_size, void* d_ws, size_t ws_size,
                              hipStream_t stream){
  const float* center = (const float*)d_in[0];
  const float* nbr    = (const float*)d_in[1];
  const float* ew     = (const float*)d_in[2];
  const float* Wq     = (const float*)d_in[3];
  const float* Wk     = (const float*)d_in[4];
  const float* Wv     = (const float*)d_in[5];
  const float* Wc     = (const float*)d_in[6];
  const float* Wx     = (const float*)d_in[7];
  const float* gamma  = (const float*)d_in[8];
  const float* beta   = (const float*)d_in[9];
  (void)in_sizes; (void)n_in; (void)out_size;

  float* W = (float*)d_ws;   // exactly 1 MiB of workspace
  (void)ws_size;

  prep_kernel<<<1024, 256, 0, stream>>>(Wq, Wk, Wv, Wc, Wx, W);
  fused_kernel<<<Bsz/BR, 256, 0, stream>>>(center, nbr, ew, gamma, beta, W, (float*)d_out);
}

// Round 8
// 1382.721 us; speedup vs baseline: 1.2184x; 1.2181x over previous
//
#include <hip/hip_runtime.h>

// B=32768, K=16, D=256, H=2, HD=128
#define Bsz 32768
#define BR  16           // rows per block
#define SCALE 0.08838834764831845f   // 1/sqrt(128)

typedef __attribute__((ext_vector_type(4))) float f32x4;
typedef __attribute__((ext_vector_type(4))) unsigned short us4;
typedef __attribute__((ext_vector_type(8))) unsigned short us8;

static __device__ __forceinline__ unsigned short f2bf(float x){
  unsigned int u = __builtin_bit_cast(unsigned int, x);
  u += 0x7FFFu + ((u >> 16) & 1u);          // RNE
  return (unsigned short)(u >> 16);
}
static __device__ __forceinline__ float bf2f(unsigned short h){
  unsigned int u = ((unsigned int)h) << 16;
  return __builtin_bit_cast(float, u);
}

// ---------------------------------------------------------------------------
// Prep (identical to passing rounds 5/6/7): fp32 weights, k-major.
//   W1T f32 [256][640]: n<512 -> M_h[k][m] (m=n&255,h=n>>8); 512..639 -> Wc
//   W2T f32 [256][256]: Wv transposed;  W3T f32 [256][128]: Wx transposed
// ---------------------------------------------------------------------------
__global__ void prep_kernel(const float* __restrict__ Wq, const float* __restrict__ Wk,
                            const float* __restrict__ Wv, const float* __restrict__ Wc,
                            const float* __restrict__ Wx, float* __restrict__ wsf){
  float* W1T = wsf;                  // [256][640]
  float* W2T = wsf + 256*640;        // [256][256]
  float* W3T = W2T + 256*256;        // [256][128]
  const int n = blockIdx.x;
  const int k = threadIdx.x;
  if (n < 512){
    const int h = n >> 8, m = n & 255;
    const float* wq = Wq + h*128*256 + k;
    const float* wk = Wk + h*128*256 + m;
    float s = 0.f;
    for (int d = 0; d < 128; ++d) s += wq[d*256] * wk[d*256];
    W1T[k*640 + n] = s;
  } else if (n < 640){
    W1T[k*640 + n] = Wc[(n-512)*256 + k];
  } else if (n < 896){
    const int r = n - 640;
    W2T[k*256 + r] = Wv[r*256 + k];
  } else {
    const int r = n - 896;
    W3T[k*128 + r] = Wx[r*256 + k];
  }
}

// ---------------------------------------------------------------------------
// Fused kernel, BR=16, 256 threads (4 waves), COLUMN-SPLIT waves in A/C/E:
// wave w owns cols [w*160,+160) of W1T / [w*64,+64) of W2T / [w*32,+32) of W3T.
// Thread in A/C/E: (lr,lc) = (lane>>2, lane&3): row lr, cols ...+lc*4.
// LDS (32.75 KB -> 4 blocks/CU):
//   s_cb   bf16 [16][264]: center (stage..A)
//   s_ctil bf16 [16][520]: ctil (A..B) -> agg overlay (B..C) -> ctx_n (D..E)
//   s_ctx  bf16 [16][264]: ctx (C..D)
// Barriers: stage|A, A|B, B|C, C|D, D|E.
// ---------------------------------------------------------------------------
__global__ __launch_bounds__(256, 4) void fused_kernel(
    const float* __restrict__ center, const float* __restrict__ nbr,
    const float* __restrict__ ew, const float* __restrict__ gamma,
    const float* __restrict__ beta, const float* __restrict__ Wall,
    float* __restrict__ out)
{
  __shared__ __align__(16) unsigned short s_cb[BR*264];
  __shared__ __align__(16) unsigned short s_ctil[BR*520];
  __shared__ __align__(16) unsigned short s_ctx[BR*264];

  const int tid  = threadIdx.x;
  const int wid  = tid >> 6;
  const int lane = tid & 63;
  const int b0   = blockIdx.x * BR;

  const float* W1T = Wall;               // [256][640]
  const float* W2T = Wall + 256*640;     // [256][256]
  const float* W3T = W2T + 256*256;      // [256][128]

  const int lr = lane >> 2;    // 0..15 (row in A/C/E)
  const int lc = lane & 3;     // 0..3  (col quad in A/C/E)

  // ---- stage center -> bf16 LDS ----
  {
    const int sr = tid >> 4;
    const int sc = (tid & 15) * 16;
    const float* cp = center + ((long)(b0 + sr) << 8) + sc;
    #pragma unroll
    for (int it = 0; it < 2; ++it){
      float4 a = *(const float4*)(cp + it*8);
      float4 b = *(const float4*)(cp + it*8 + 4);
      us8 v;
      v[0]=f2bf(a.x); v[1]=f2bf(a.y); v[2]=f2bf(a.z); v[3]=f2bf(a.w);
      v[4]=f2bf(b.x); v[5]=f2bf(b.y); v[6]=f2bf(b.z); v[7]=f2bf(b.w);
      *(us8*)&s_cb[sr*264 + sc + it*8] = v;
    }
  }
  __syncthreads();

  // ---- Phase A: [16x256]@[256x640]; wave w -> cols [w*160,+160) ----
  {
    f32x4 acc[10];
    #pragma unroll
    for (int t = 0; t < 10; ++t) acc[t] = (f32x4){0,0,0,0};
    const float* wbase = W1T + wid*160 + lc*4;
    #pragma unroll 2
    for (int k = 0; k < 256; ++k){
      const float a = bf2f(s_cb[lr*264 + k]);
      const f32x4* wp = (const f32x4*)(wbase + k*640);
      #pragma unroll
      for (int t = 0; t < 10; ++t)
        acc[t] += a * wp[t*4];          // +t*16 floats (64B imm offsets)
    }
    const int colbase = wid*160 + lc*4;
    #pragma unroll
    for (int t = 0; t < 10; ++t){
      const int col = colbase + t*16;
      if (col < 512){
        us4 v;
        #pragma unroll
        for (int j = 0; j < 4; ++j) v[j] = f2bf(acc[t][j]);
        *(us4*)&s_ctil[lr*520 + col] = v;
      } else {
        *(f32x4*)&out[((long)(b0 + lr) << 8) + (col - 512)] = acc[t];
      }
    }
  }
  __syncthreads();

  // ---- Phase B: attention, 4 rows/wave; agg bf16 overlays own ctil cells ----
  {
    #pragma unroll 1
    for (int rr = 0; rr < 4; ++rr){
      const int r = wid*4 + rr;
      const long b = b0 + r;
      float4 c0, c1;
      {
        us4 h0 = *(const us4*)&s_ctil[r*520 + lane*4];
        us4 h1 = *(const us4*)&s_ctil[r*520 + 256 + lane*4];
        c0.x=bf2f(h0[0]); c0.y=bf2f(h0[1]); c0.z=bf2f(h0[2]); c0.w=bf2f(h0[3]);
        c1.x=bf2f(h1[0]); c1.y=bf2f(h1[1]); c1.z=bf2f(h1[2]); c1.w=bf2f(h1[3]);
      }
      const float4* ewp = (const float4*)(ew + b*16);
      float er[16];
      #pragma unroll
      for (int j = 0; j < 4; ++j){
        float4 e = ewp[j];
        er[4*j]=e.x; er[4*j+1]=e.y; er[4*j+2]=e.z; er[4*j+3]=e.w;
      }
      const float* npt = nbr + ((b << 4) << 8) + lane*4;
      float sum0 = 0.f, sum1 = 0.f;
      float4 agg0 = {0,0,0,0}, agg1 = {0,0,0,0};
      #pragma unroll 1
      for (int half = 0; half < 2; ++half){
        float4 xv[8];
        #pragma unroll
        for (int k = 0; k < 8; ++k) xv[k] = *(const float4*)(npt + ((half*8 + k) << 8));
        #pragma unroll
        for (int k = 0; k < 8; ++k){
          float p0 = xv[k].x*c0.x + xv[k].y*c0.y + xv[k].z*c0.z + xv[k].w*c0.w;
          float p1 = xv[k].x*c1.x + xv[k].y*c1.y + xv[k].z*c1.z + xv[k].w*c1.w;
          #pragma unroll
          for (int m = 32; m >= 1; m >>= 1){
            p0 += __shfl_xor(p0, m, 64);
            p1 += __shfl_xor(p1, m, 64);
          }
          const float w0 = __expf(p0*SCALE + er[half*8 + k]);  // scores O(1)
          const float w1 = __expf(p1*SCALE + er[half*8 + k]);
          sum0 += w0; sum1 += w1;
          agg0.x += w0*xv[k].x; agg0.y += w0*xv[k].y; agg0.z += w0*xv[k].z; agg0.w += w0*xv[k].w;
          agg1.x += w1*xv[k].x; agg1.y += w1*xv[k].y; agg1.z += w1*xv[k].z; agg1.w += w1*xv[k].w;
        }
      }
      const float i0 = 1.0f / sum0, i1 = 1.0f / sum1;
      us4 v0, v1;
      v0[0]=f2bf(agg0.x*i0); v0[1]=f2bf(agg0.y*i0); v0[2]=f2bf(agg0.z*i0); v0[3]=f2bf(agg0.w*i0);
      v1[0]=f2bf(agg1.x*i1); v1[1]=f2bf(agg1.y*i1); v1[2]=f2bf(agg1.z*i1); v1[3]=f2bf(agg1.w*i1);
      *(us4*)&s_ctil[r*520 + lane*4]       = v0;   // same cells this lane read (WAR ok)
      *(us4*)&s_ctil[r*520 + 256 + lane*4] = v1;
    }
  }
  __syncthreads();

  // ---- Phase C: ctx = agg_h @ Wv_h^T; wave w -> cols [w*64,+64), head w>>1 ----
  {
    f32x4 cacc[4];
    #pragma unroll
    for (int t = 0; t < 4; ++t) cacc[t] = (f32x4){0,0,0,0};
    const int h = wid >> 1;
    const float* wbase = W2T + wid*64 + lc*4;
    #pragma unroll 2
    for (int k = 0; k < 256; ++k){
      const float a = bf2f(s_ctil[lr*520 + h*256 + k]);
      const f32x4* wp = (const f32x4*)(wbase + (k << 8));
      #pragma unroll
      for (int t = 0; t < 4; ++t)
        cacc[t] += a * wp[t*4];
    }
    #pragma unroll
    for (int t = 0; t < 4; ++t){
      us4 v;
      #pragma unroll
      for (int j = 0; j < 4; ++j) v[j] = f2bf(cacc[t][j]);
      *(us4*)&s_ctx[lr*264 + wid*64 + t*16 + lc*4] = v;
    }
  }
  __syncthreads();

  // ---- Phase D: LayerNorm, 4 rows/wave; ctx_n bf16 -> s_ctil[.][0..255] ----
  {
    #pragma unroll 1
    for (int rr = 0; rr < 4; ++rr){
      const int r = wid*4 + rr;
      us4 xh = *(const us4*)&s_ctx[r*264 + lane*4];
      float4 x;
      x.x = bf2f(xh[0]); x.y = bf2f(xh[1]); x.z = bf2f(xh[2]); x.w = bf2f(xh[3]);
      float s = x.x + x.y + x.z + x.w;
      float q = x.x*x.x + x.y*x.y + x.z*x.z + x.w*x.w;
      #pragma unroll
      for (int m = 32; m >= 1; m >>= 1){
        s += __shfl_xor(s, m, 64);
        q += __shfl_xor(q, m, 64);
      }
      const float mu  = s * (1.f/256.f);
      const float var = q * (1.f/256.f) - mu*mu;
      const float rs  = rsqrtf(var + 1e-5f);
      const float4 g  = *(const float4*)(gamma + lane*4);
      const float4 bb = *(const float4*)(beta  + lane*4);
      us4 v;
      v[0] = f2bf((x.x - mu)*rs*g.x + bb.x);
      v[1] = f2bf((x.y - mu)*rs*g.y + bb.y);
      v[2] = f2bf((x.z - mu)*rs*g.z + bb.z);
      v[3] = f2bf((x.w - mu)*rs*g.w + bb.w);
      *(us4*)&s_ctil[r*520 + lane*4] = v;
    }
  }
  __syncthreads();

  // ---- Phase E: out-right = ctx_n @ Wx^T; wave w -> cols [w*32,+32) ----
  {
    f32x4 e0 = {0,0,0,0}, e1 = {0,0,0,0};
    const float* wbase = W3T + wid*32 + lc*4;
    #pragma unroll 2
    for (int k = 0; k < 256; ++k){
      const float a = bf2f(s_ctil[lr*520 + k]);
      const f32x4* wp = (const f32x4*)(wbase + (k << 7));
      e0 += a * wp[0];
      e1 += a * wp[4];
    }
    float* op = out + ((long)(b0 + lr) << 8) + 128 + wid*32 + lc*4;
    *(f32x4*)(op)      = e0;
    *(f32x4*)(op + 16) = e1;
  }
}

extern "C" void kernel_launch(void* const* d_in, const int* in_sizes, int n_in,
                              void* d_out, int out_size, void* d_ws, size_t ws_size,
                              hipStream_t stream){
  const float* center = (const float*)d_in[0];
  const float* nbr    = (const float*)d_in[1];
  const float* ew     = (const float*)d_in[2];
  const float* Wq     = (const float*)d_in[3];
  const float* Wk     = (const float*)d_in[4];
  const float* Wv     = (const float*)d_in[5];
  const float* Wc     = (const float*)d_in[6];
  const float* Wx     = (const float*)d_in[7];
  const float* gamma  = (const float*)d_in[8];
  const float* beta   = (const float*)d_in[9];
  (void)in_sizes; (void)n_in; (void)out_size;

  float* W = (float*)d_ws;   // exactly 1 MiB of workspace
  (void)ws_size;

  prep_kernel<<<1024, 256, 0, stream>>>(Wq, Wk, Wv, Wc, Wx, W);
  fused_kernel<<<Bsz/BR, 256, 0, stream>>>(center, nbr, ew, gamma, beta, W, (float*)d_out);
}

// Round 9
// 474.487 us; speedup vs baseline: 3.5505x; 2.9141x over previous
//
#include <hip/hip_runtime.h>

// B=32768, K=16, D=256, H=2, HD=128
#define Bsz 32768
#define BR  32           // rows per block; 8 rows per wave, wave-autonomous
#define SCALE 0.08838834764831845f   // 1/sqrt(128)

typedef __attribute__((ext_vector_type(4))) float f32x4;
typedef __attribute__((ext_vector_type(4))) unsigned short us4;
typedef __attribute__((ext_vector_type(8))) unsigned short us8;

static __device__ __forceinline__ unsigned short f2bf(float x){
  unsigned int u = __builtin_bit_cast(unsigned int, x);
  u += 0x7FFFu + ((u >> 16) & 1u);          // RNE
  return (unsigned short)(u >> 16);
}
static __device__ __forceinline__ float bf2f(unsigned short h){
  unsigned int u = ((unsigned int)h) << 16;
  return __builtin_bit_cast(float, u);
}

// ---------------------------------------------------------------------------
// Prep (identical to passing rounds 5-8): fp32 weights, k-major.
//   W1T f32 [256][640]: n<512 -> M_h[k][m] (m=n&255,h=n>>8); 512..639 -> Wc
//   W2T f32 [256][256]: Wv transposed;  W3T f32 [256][128]: Wx transposed
// ---------------------------------------------------------------------------
__global__ void prep_kernel(const float* __restrict__ Wq, const float* __restrict__ Wk,
                            const float* __restrict__ Wv, const float* __restrict__ Wc,
                            const float* __restrict__ Wx, float* __restrict__ wsf){
  float* W1T = wsf;                  // [256][640]
  float* W2T = wsf + 256*640;        // [256][256]
  float* W3T = W2T + 256*256;        // [256][128]
  const int n = blockIdx.x;
  const int k = threadIdx.x;
  if (n < 512){
    const int h = n >> 8, m = n & 255;
    const float* wq = Wq + h*128*256 + k;
    const float* wk = Wk + h*128*256 + m;
    float s = 0.f;
    for (int d = 0; d < 128; ++d) s += wq[d*256] * wk[d*256];
    W1T[k*640 + n] = s;
  } else if (n < 640){
    W1T[k*640 + n] = Wc[(n-512)*256 + k];
  } else if (n < 896){
    const int r = n - 640;
    W2T[k*256 + r] = Wv[r*256 + k];
  } else {
    const int r = n - 896;
    W3T[k*128 + r] = Wx[r*256 + k];
  }
}

// ---------------------------------------------------------------------------
// Fused kernel, BR=32, 256 threads (4 waves), ZERO BARRIERS:
// wave w owns rows 8w..8w+7 through every phase (stage, A, B, C, D, E),
// so all LDS traffic is wave-local and waves free-run (latency hiding by
// desynchronization instead of barrier-lockstep).
// Thread (rt,ct) = (tid>>5, tid&31): rows 4rt..4rt+3, col quads ct*4 + t*128.
// LDS (49 KB -> 3 blocks/CU):
//   s_cb   bf16 [32][264]: center (stage..A); ctx overlay (C..D)
//   s_ctil bf16 [32][520]: ctil (A..B) -> agg overlay (B..C) -> ctx_n (D..E)
// ---------------------------------------------------------------------------
__global__ __launch_bounds__(256, 3) void fused_kernel(
    const float* __restrict__ center, const float* __restrict__ nbr,
    const float* __restrict__ ew, const float* __restrict__ gamma,
    const float* __restrict__ beta, const float* __restrict__ Wall,
    float* __restrict__ out)
{
  __shared__ __align__(16) unsigned short s_cb[BR*264];
  __shared__ __align__(16) unsigned short s_ctil[BR*520];

  const int tid  = threadIdx.x;
  const int wid  = tid >> 6;
  const int lane = tid & 63;
  const int b0   = blockIdx.x * BR;

  const float* W1T = Wall;               // [256][640]
  const float* W2T = Wall + 256*640;     // [256][256]
  const float* W3T = W2T + 256*256;      // [256][128]

  const int rt = tid >> 5;     // 0..7  (row group: rows 4rt..4rt+3)
  const int ct = tid & 31;     // 0..31 (col quad)

  // ---- stage center rows 8w..8w+7 -> bf16 LDS (wave-local) ----
  {
    const int sr = tid >> 3;            // 0..31 ; wave w -> rows 8w..8w+7
    const int sc = (tid & 7) * 32;      // 0..224
    const float* cp = center + ((long)(b0 + sr) << 8) + sc;
    #pragma unroll
    for (int it = 0; it < 4; ++it){
      float4 a = *(const float4*)(cp + it*8);
      float4 b = *(const float4*)(cp + it*8 + 4);
      us8 v;
      v[0]=f2bf(a.x); v[1]=f2bf(a.y); v[2]=f2bf(a.z); v[3]=f2bf(a.w);
      v[4]=f2bf(b.x); v[5]=f2bf(b.y); v[6]=f2bf(b.z); v[7]=f2bf(b.w);
      *(us8*)&s_cb[sr*264 + sc + it*8] = v;
    }
  }
  // no barrier: phase A reads only rows this wave staged

  // ---- Phase A: [32x256]@[256x640] -> ctil bf16 + out-left; 4 rows/thread ----
  // thread cols: t*128 + ct*4 + j, t=0..4 (t==4 -> out-left cols 512..639)
  {
    f32x4 acc[4][5];
    #pragma unroll
    for (int rr = 0; rr < 4; ++rr)
      #pragma unroll
      for (int t = 0; t < 5; ++t) acc[rr][t] = (f32x4){0,0,0,0};
    #pragma unroll 2
    for (int k = 0; k < 256; ++k){
      float a[4];
      #pragma unroll
      for (int rr = 0; rr < 4; ++rr) a[rr] = bf2f(s_cb[(4*rt+rr)*264 + k]);
      const float* wrow = W1T + k*640;
      f32x4 w[5];
      #pragma unroll
      for (int t = 0; t < 5; ++t) w[t] = *((const f32x4*)(wrow + t*128) + ct);
      #pragma unroll
      for (int rr = 0; rr < 4; ++rr)
        #pragma unroll
        for (int t = 0; t < 5; ++t)
          acc[rr][t] += a[rr] * w[t];
    }
    #pragma unroll
    for (int rr = 0; rr < 4; ++rr){
      const int r = 4*rt + rr;
      #pragma unroll
      for (int t = 0; t < 4; ++t){
        us4 v;
        #pragma unroll
        for (int j = 0; j < 4; ++j) v[j] = f2bf(acc[rr][t][j]);
        *(us4*)&s_ctil[r*520 + t*128 + ct*4] = v;
      }
      *(f32x4*)&out[((long)(b0 + r) << 8) + ct*4] = acc[rr][4];
    }
  }
  // no barrier: ctil rows 8w..8w+7 written and read by wave w only

  // ---- Phase B: attention, 8 rows/wave; agg bf16 overlays own ctil cells ----
  {
    #pragma unroll 1
    for (int rr = 0; rr < 8; ++rr){
      const int r = wid*8 + rr;
      const long b = b0 + r;
      float4 c0, c1;
      {
        us4 h0 = *(const us4*)&s_ctil[r*520 + lane*4];
        us4 h1 = *(const us4*)&s_ctil[r*520 + 256 + lane*4];
        c0.x=bf2f(h0[0]); c0.y=bf2f(h0[1]); c0.z=bf2f(h0[2]); c0.w=bf2f(h0[3]);
        c1.x=bf2f(h1[0]); c1.y=bf2f(h1[1]); c1.z=bf2f(h1[2]); c1.w=bf2f(h1[3]);
      }
      const float4* ewp = (const float4*)(ew + b*16);
      float er[16];
      #pragma unroll
      for (int j = 0; j < 4; ++j){
        float4 e = ewp[j];
        er[4*j]=e.x; er[4*j+1]=e.y; er[4*j+2]=e.z; er[4*j+3]=e.w;
      }
      float4 xv[16];
      const float* npt = nbr + ((b << 4) << 8) + lane*4;
      #pragma unroll
      for (int k = 0; k < 16; ++k) xv[k] = *(const float4*)(npt + (k << 8));
      float sum0 = 0.f, sum1 = 0.f;
      float4 agg0 = {0,0,0,0}, agg1 = {0,0,0,0};
      #pragma unroll
      for (int k = 0; k < 16; ++k){
        float p0 = xv[k].x*c0.x + xv[k].y*c0.y + xv[k].z*c0.z + xv[k].w*c0.w;
        float p1 = xv[k].x*c1.x + xv[k].y*c1.y + xv[k].z*c1.z + xv[k].w*c1.w;
        #pragma unroll
        for (int m = 32; m >= 1; m >>= 1){
          p0 += __shfl_xor(p0, m, 64);
          p1 += __shfl_xor(p1, m, 64);
        }
        const float w0 = __expf(p0*SCALE + er[k]);   // scores O(1): no max-sub
        const float w1 = __expf(p1*SCALE + er[k]);
        sum0 += w0; sum1 += w1;
        agg0.x += w0*xv[k].x; agg0.y += w0*xv[k].y; agg0.z += w0*xv[k].z; agg0.w += w0*xv[k].w;
        agg1.x += w1*xv[k].x; agg1.y += w1*xv[k].y; agg1.z += w1*xv[k].z; agg1.w += w1*xv[k].w;
      }
      const float i0 = 1.0f / sum0, i1 = 1.0f / sum1;
      us4 v0, v1;
      v0[0]=f2bf(agg0.x*i0); v0[1]=f2bf(agg0.y*i0); v0[2]=f2bf(agg0.z*i0); v0[3]=f2bf(agg0.w*i0);
      v1[0]=f2bf(agg1.x*i1); v1[1]=f2bf(agg1.y*i1); v1[2]=f2bf(agg1.z*i1); v1[3]=f2bf(agg1.w*i1);
      *(us4*)&s_ctil[r*520 + lane*4]       = v0;   // same cells this lane read (WAR ok)
      *(us4*)&s_ctil[r*520 + 256 + lane*4] = v1;
    }
  }
  // no barrier: agg rows are wave-local

  // ---- Phase C: ctx = agg_h @ Wv_h^T; 4 rows/thread, cols t*128+ct*4, t=head ----
  {
    f32x4 cacc[4][2];
    #pragma unroll
    for (int rr = 0; rr < 4; ++rr){ cacc[rr][0] = (f32x4){0,0,0,0}; cacc[rr][1] = (f32x4){0,0,0,0}; }
    #pragma unroll 2
    for (int k = 0; k < 256; ++k){
      float a0[4], a1[4];
      #pragma unroll
      for (int rr = 0; rr < 4; ++rr){
        a0[rr] = bf2f(s_ctil[(4*rt+rr)*520 + k]);
        a1[rr] = bf2f(s_ctil[(4*rt+rr)*520 + 256 + k]);
      }
      const float* wrow = W2T + (k << 8);
      const f32x4 w0 = *((const f32x4*)(wrow)       + ct);
      const f32x4 w1 = *((const f32x4*)(wrow + 128) + ct);
      #pragma unroll
      for (int rr = 0; rr < 4; ++rr){
        cacc[rr][0] += a0[rr] * w0;
        cacc[rr][1] += a1[rr] * w1;
      }
    }
    #pragma unroll
    for (int rr = 0; rr < 4; ++rr){
      const int r = 4*rt + rr;
      #pragma unroll
      for (int t = 0; t < 2; ++t){
        us4 v;
        #pragma unroll
        for (int j = 0; j < 4; ++j) v[j] = f2bf(cacc[rr][t][j]);
        *(us4*)&s_cb[r*264 + t*128 + ct*4] = v;    // ctx overlays dead center
      }
    }
  }
  // no barrier: ctx rows wave-local

  // ---- Phase D: LayerNorm, 8 rows/wave; ctx_n bf16 -> s_ctil[.][0..255] ----
  {
    #pragma unroll 1
    for (int rr = 0; rr < 8; ++rr){
      const int r = wid*8 + rr;
      us4 xh = *(const us4*)&s_cb[r*264 + lane*4];
      float4 x;
      x.x = bf2f(xh[0]); x.y = bf2f(xh[1]); x.z = bf2f(xh[2]); x.w = bf2f(xh[3]);
      float s = x.x + x.y + x.z + x.w;
      float q = x.x*x.x + x.y*x.y + x.z*x.z + x.w*x.w;
      #pragma unroll
      for (int m = 32; m >= 1; m >>= 1){
        s += __shfl_xor(s, m, 64);
        q += __shfl_xor(q, m, 64);
      }
      const float mu  = s * (1.f/256.f);
      const float var = q * (1.f/256.f) - mu*mu;
      const float rs  = rsqrtf(var + 1e-5f);
      const float4 g  = *(const float4*)(gamma + lane*4);
      const float4 bb = *(const float4*)(beta  + lane*4);
      us4 v;
      v[0] = f2bf((x.x - mu)*rs*g.x + bb.x);
      v[1] = f2bf((x.y - mu)*rs*g.y + bb.y);
      v[2] = f2bf((x.z - mu)*rs*g.z + bb.z);
      v[3] = f2bf((x.w - mu)*rs*g.w + bb.w);
      *(us4*)&s_ctil[r*520 + lane*4] = v;          // agg region, dead after C
    }
  }
  // no barrier: ctx_n rows wave-local

  // ---- Phase E: out-right = ctx_n @ Wx^T; 4 rows/thread, cols ct*4 ----
  {
    f32x4 eacc[4];
    #pragma unroll
    for (int rr = 0; rr < 4; ++rr) eacc[rr] = (f32x4){0,0,0,0};
    #pragma unroll 2
    for (int k = 0; k < 256; ++k){
      float a[4];
      #pragma unroll
      for (int rr = 0; rr < 4; ++rr) a[rr] = bf2f(s_ctil[(4*rt+rr)*520 + k]);
      const f32x4 w = *((const f32x4*)(W3T + (k << 7)) + ct);
      #pragma unroll
      for (int rr = 0; rr < 4; ++rr) eacc[rr] += a[rr] * w;
    }
    #pragma unroll
    for (int rr = 0; rr < 4; ++rr)
      *(f32x4*)&out[((long)(b0 + 4*rt + rr) << 8) + 128 + ct*4] = eacc[rr];
  }
}

extern "C" void kernel_launch(void* const* d_in, const int* in_sizes, int n_in,
                              void* d_out, int out_size, void* d_ws, size_t ws_size,
                              hipStream_t stream){
  const float* center = (const float*)d_in[0];
  const float* nbr    = (const float*)d_in[1];
  const float* ew     = (const float*)d_in[2];
  const float* Wq     = (const float*)d_in[3];
  const float* Wk     = (const float*)d_in[4];
  const float* Wv     = (const float*)d_in[5];
  const float* Wc     = (const float*)d_in[6];
  const float* Wx     = (const float*)d_in[7];
  const float* gamma  = (const float*)d_in[8];
  const float* beta   = (const float*)d_in[9];
  (void)in_sizes; (void)n_in; (void)out_size;

  float* W = (float*)d_ws;   // exactly 1 MiB of workspace
  (void)ws_size;

  prep_kernel<<<1024, 256, 0, stream>>>(Wq, Wk, Wv, Wc, Wx, W);
  fused_kernel<<<Bsz/BR, 256, 0, stream>>>(center, nbr, ew, gamma, beta, W, (float*)d_out);
}

// Round 10
// 452.897 us; speedup vs baseline: 3.7197x; 1.0477x over previous
//
#include <hip/hip_runtime.h>

// B=32768, K=16, D=256, H=2, HD=128
#define Bsz 32768
#define BR  32           // rows per block; 8 rows per wave, wave-autonomous
#define SCALE 0.08838834764831845f   // 1/sqrt(128)

typedef __attribute__((ext_vector_type(4))) float f32x4;
typedef __attribute__((ext_vector_type(4))) unsigned short us4;
typedef __attribute__((ext_vector_type(8))) unsigned short us8;

static __device__ __forceinline__ unsigned short f2bf(float x){
  unsigned int u = __builtin_bit_cast(unsigned int, x);
  u += 0x7FFFu + ((u >> 16) & 1u);          // RNE
  return (unsigned short)(u >> 16);
}
static __device__ __forceinline__ float bf2f(unsigned short h){
  unsigned int u = ((unsigned int)h) << 16;
  return __builtin_bit_cast(float, u);
}

// ---------------------------------------------------------------------------
// Prep (identical to passing rounds 5-9): fp32 weights, k-major.
//   W1T f32 [256][640]: n<512 -> M_h[k][m] (m=n&255,h=n>>8); 512..639 -> Wc
//   W2T f32 [256][256]: Wv transposed;  W3T f32 [256][128]: Wx transposed
// ---------------------------------------------------------------------------
__global__ void prep_kernel(const float* __restrict__ Wq, const float* __restrict__ Wk,
                            const float* __restrict__ Wv, const float* __restrict__ Wc,
                            const float* __restrict__ Wx, float* __restrict__ wsf){
  float* W1T = wsf;                  // [256][640]
  float* W2T = wsf + 256*640;        // [256][256]
  float* W3T = W2T + 256*256;        // [256][128]
  const int n = blockIdx.x;
  const int k = threadIdx.x;
  if (n < 512){
    const int h = n >> 8, m = n & 255;
    const float* wq = Wq + h*128*256 + k;
    const float* wk = Wk + h*128*256 + m;
    float s = 0.f;
    for (int d = 0; d < 128; ++d) s += wq[d*256] * wk[d*256];
    W1T[k*640 + n] = s;
  } else if (n < 640){
    W1T[k*640 + n] = Wc[(n-512)*256 + k];
  } else if (n < 896){
    const int r = n - 640;
    W2T[k*256 + r] = Wv[r*256 + k];
  } else {
    const int r = n - 896;
    W3T[k*128 + r] = Wx[r*256 + k];
  }
}

// ---------------------------------------------------------------------------
// Fused kernel, BR=32, 256 threads (4 waves), ZERO BARRIERS (wave w owns rows
// 8w..8w+7 through all phases). DS-diet version of round 9:
//  - A/C/E read activations via ds_read_b128 (8 bf16) + VALU unpack
//  - B uses reduce-scatter (32 shuffles/row) + 1 exp/lane + LDS w-broadcast
// LDS (50.2 KB -> 3 blocks/CU):
//   s_cb   bf16 [32][264]: center (stage..A); per-row w-buffer (B); ctx (C..D)
//   s_ctil bf16 [32][520]: ctil (A..B) -> agg overlay (B..C) -> ctx_n (D..E)
// ---------------------------------------------------------------------------
__global__ __launch_bounds__(256, 3) void fused_kernel(
    const float* __restrict__ center, const float* __restrict__ nbr,
    const float* __restrict__ ew, const float* __restrict__ gamma,
    const float* __restrict__ beta, const float* __restrict__ Wall,
    float* __restrict__ out)
{
  __shared__ __align__(16) unsigned short s_cb[BR*264];
  __shared__ __align__(16) unsigned short s_ctil[BR*520];

  const int tid  = threadIdx.x;
  const int wid  = tid >> 6;
  const int lane = tid & 63;
  const int b0   = blockIdx.x * BR;

  const float* W1T = Wall;               // [256][640]
  const float* W2T = Wall + 256*640;     // [256][256]
  const float* W3T = W2T + 256*256;      // [256][128]

  const int rt = tid >> 5;     // 0..7  (row group: rows 4rt..4rt+3)
  const int ct = tid & 31;     // 0..31 (col quad)

  // ---- stage center rows 8w..8w+7 -> bf16 LDS (wave-local) ----
  {
    const int sr = tid >> 3;            // 0..31 ; wave w -> rows 8w..8w+7
    const int sc = (tid & 7) * 32;      // 0..224
    const float* cp = center + ((long)(b0 + sr) << 8) + sc;
    #pragma unroll
    for (int it = 0; it < 4; ++it){
      float4 a = *(const float4*)(cp + it*8);
      float4 b = *(const float4*)(cp + it*8 + 4);
      us8 v;
      v[0]=f2bf(a.x); v[1]=f2bf(a.y); v[2]=f2bf(a.z); v[3]=f2bf(a.w);
      v[4]=f2bf(b.x); v[5]=f2bf(b.y); v[6]=f2bf(b.z); v[7]=f2bf(b.w);
      *(us8*)&s_cb[sr*264 + sc + it*8] = v;
    }
  }
  // no barrier: phase A reads only rows this wave staged

  // ---- Phase A: [32x256]@[256x640] -> ctil bf16 + out-left; 4 rows/thread ----
  {
    f32x4 acc[4][5];
    #pragma unroll
    for (int rr = 0; rr < 4; ++rr)
      #pragma unroll
      for (int t = 0; t < 5; ++t) acc[rr][t] = (f32x4){0,0,0,0};
    #pragma unroll 1
    for (int k0 = 0; k0 < 256; k0 += 8){
      us8 a8[4];
      #pragma unroll
      for (int rr = 0; rr < 4; ++rr)
        a8[rr] = *(const us8*)&s_cb[(4*rt+rr)*264 + k0];
      #pragma unroll
      for (int kk = 0; kk < 8; ++kk){
        float a[4];
        #pragma unroll
        for (int rr = 0; rr < 4; ++rr) a[rr] = bf2f(a8[rr][kk]);
        const float* wrow = W1T + (k0+kk)*640;
        f32x4 w[5];
        #pragma unroll
        for (int t = 0; t < 5; ++t) w[t] = *((const f32x4*)(wrow + t*128) + ct);
        #pragma unroll
        for (int rr = 0; rr < 4; ++rr)
          #pragma unroll
          for (int t = 0; t < 5; ++t)
            acc[rr][t] += a[rr] * w[t];
      }
    }
    #pragma unroll
    for (int rr = 0; rr < 4; ++rr){
      const int r = 4*rt + rr;
      #pragma unroll
      for (int t = 0; t < 4; ++t){
        us4 v;
        #pragma unroll
        for (int j = 0; j < 4; ++j) v[j] = f2bf(acc[rr][t][j]);
        *(us4*)&s_ctil[r*520 + t*128 + ct*4] = v;
      }
      *(f32x4*)&out[((long)(b0 + r) << 8) + ct*4] = acc[rr][4];
    }
  }
  // no barrier: ctil rows wave-local

  // ---- Phase B: attention, 8 rows/wave; reduce-scatter scores ----
  {
    const int myk = ((lane>>4)&1)*8 + ((lane>>3)&1)*4 + ((lane>>2)&1)*2 + ((lane>>1)&1);
    const int myh = lane >> 5;
    #pragma unroll 1
    for (int rr = 0; rr < 8; ++rr){
      const int r = wid*8 + rr;
      const long b = b0 + r;
      float4 c0, c1;
      {
        us4 h0 = *(const us4*)&s_ctil[r*520 + lane*4];
        us4 h1 = *(const us4*)&s_ctil[r*520 + 256 + lane*4];
        c0.x=bf2f(h0[0]); c0.y=bf2f(h0[1]); c0.z=bf2f(h0[2]); c0.w=bf2f(h0[3]);
        c1.x=bf2f(h1[0]); c1.y=bf2f(h1[1]); c1.z=bf2f(h1[2]); c1.w=bf2f(h1[3]);
      }
      float4 xv[16];
      const float* npt = nbr + ((b << 4) << 8) + lane*4;
      #pragma unroll
      for (int k = 0; k < 16; ++k) xv[k] = *(const float4*)(npt + (k << 8));
      // per-lane 4-dim partials for all 32 (head,k)
      float P0[16], P1[16];
      #pragma unroll
      for (int k = 0; k < 16; ++k){
        P0[k] = xv[k].x*c0.x + xv[k].y*c0.y + xv[k].z*c0.z + xv[k].w*c0.w;
        P1[k] = xv[k].x*c1.x + xv[k].y*c1.y + xv[k].z*c1.z + xv[k].w*c1.w;
      }
      // reduce-scatter: masks 32,16,8,4,2 then final allpair 1
      const int b5 = lane & 32, b4 = lane & 16, b3 = lane & 8, b2 = lane & 4, b1 = lane & 2;
      float Q[16];
      #pragma unroll
      for (int j = 0; j < 16; ++j){
        const float give = b5 ? P0[j] : P1[j];
        const float keep = b5 ? P1[j] : P0[j];
        Q[j] = keep + __shfl_xor(give, 32, 64);
      }
      float R[8];
      #pragma unroll
      for (int j = 0; j < 8; ++j){
        const float give = b4 ? Q[j] : Q[8+j];
        const float keep = b4 ? Q[8+j] : Q[j];
        R[j] = keep + __shfl_xor(give, 16, 64);
      }
      float S[4];
      #pragma unroll
      for (int j = 0; j < 4; ++j){
        const float give = b3 ? R[j] : R[4+j];
        const float keep = b3 ? R[4+j] : R[j];
        S[j] = keep + __shfl_xor(give, 8, 64);
      }
      float T[2];
      #pragma unroll
      for (int j = 0; j < 2; ++j){
        const float give = b2 ? S[j] : S[2+j];
        const float keep = b2 ? S[2+j] : S[j];
        T[j] = keep + __shfl_xor(give, 4, 64);
      }
      float U;
      {
        const float give = b1 ? T[0] : T[1];
        const float keep = b1 ? T[1] : T[0];
        U = keep + __shfl_xor(give, 2, 64);
      }
      const float sfull = U + __shfl_xor(U, 1, 64);   // s[myh][myk], full 64-lane sum
      // weight
      const float erk = ew[b*16 + myk];
      const float e = __expf(sfull*SCALE + erk);      // scores O(1): no max-sub
      float dn = e;
      dn += __shfl_xor(dn, 2, 64);
      dn += __shfl_xor(dn, 4, 64);
      dn += __shfl_xor(dn, 8, 64);
      dn += __shfl_xor(dn, 16, 64);
      const float w = e / dn;
      // broadcast via wave-local LDS overlay (dead center row r)
      float* wbuf = (float*)&s_cb[r*264];
      wbuf[myh*16 + myk] = w;                          // 2 lanes same addr, same value
      f32x4 wv[8];
      #pragma unroll
      for (int t = 0; t < 8; ++t) wv[t] = ((const f32x4*)wbuf)[t];
      // aggregate (weights already normalized)
      float4 agg0 = {0,0,0,0}, agg1 = {0,0,0,0};
      #pragma unroll
      for (int k = 0; k < 16; ++k){
        const float w0 = wv[k>>2][k&3];
        const float w1 = wv[4 + (k>>2)][k&3];
        agg0.x += w0*xv[k].x; agg0.y += w0*xv[k].y; agg0.z += w0*xv[k].z; agg0.w += w0*xv[k].w;
        agg1.x += w1*xv[k].x; agg1.y += w1*xv[k].y; agg1.z += w1*xv[k].z; agg1.w += w1*xv[k].w;
      }
      us4 v0, v1;
      v0[0]=f2bf(agg0.x); v0[1]=f2bf(agg0.y); v0[2]=f2bf(agg0.z); v0[3]=f2bf(agg0.w);
      v1[0]=f2bf(agg1.x); v1[1]=f2bf(agg1.y); v1[2]=f2bf(agg1.z); v1[3]=f2bf(agg1.w);
      *(us4*)&s_ctil[r*520 + lane*4]       = v0;   // same cells this lane read (WAR ok)
      *(us4*)&s_ctil[r*520 + 256 + lane*4] = v1;
    }
  }
  // no barrier: agg rows wave-local

  // ---- Phase C: ctx = agg_h @ Wv_h^T; 4 rows/thread, vectorized LDS reads ----
  {
    f32x4 cacc[4][2];
    #pragma unroll
    for (int rr = 0; rr < 4; ++rr){ cacc[rr][0] = (f32x4){0,0,0,0}; cacc[rr][1] = (f32x4){0,0,0,0}; }
    #pragma unroll 1
    for (int k0 = 0; k0 < 256; k0 += 8){
      us8 a8h0[4], a8h1[4];
      #pragma unroll
      for (int rr = 0; rr < 4; ++rr){
        a8h0[rr] = *(const us8*)&s_ctil[(4*rt+rr)*520 + k0];
        a8h1[rr] = *(const us8*)&s_ctil[(4*rt+rr)*520 + 256 + k0];
      }
      #pragma unroll
      for (int kk = 0; kk < 8; ++kk){
        const float* wrow = W2T + ((k0+kk) << 8);
        const f32x4 w0 = *((const f32x4*)(wrow)       + ct);
        const f32x4 w1 = *((const f32x4*)(wrow + 128) + ct);
        #pragma unroll
        for (int rr = 0; rr < 4; ++rr){
          cacc[rr][0] += bf2f(a8h0[rr][kk]) * w0;
          cacc[rr][1] += bf2f(a8h1[rr][kk]) * w1;
        }
      }
    }
    #pragma unroll
    for (int rr = 0; rr < 4; ++rr){
      const int r = 4*rt + rr;
      #pragma unroll
      for (int t = 0; t < 2; ++t){
        us4 v;
        #pragma unroll
        for (int j = 0; j < 4; ++j) v[j] = f2bf(cacc[rr][t][j]);
        *(us4*)&s_cb[r*264 + t*128 + ct*4] = v;    // ctx overlays dead center / wbuf
      }
    }
  }
  // no barrier: ctx rows wave-local

  // ---- Phase D: LayerNorm, 8 rows/wave; ctx_n bf16 -> s_ctil[.][0..255] ----
  {
    #pragma unroll 1
    for (int rr = 0; rr < 8; ++rr){
      const int r = wid*8 + rr;
      us4 xh = *(const us4*)&s_cb[r*264 + lane*4];
      float4 x;
      x.x = bf2f(xh[0]); x.y = bf2f(xh[1]); x.z = bf2f(xh[2]); x.w = bf2f(xh[3]);
      float s = x.x + x.y + x.z + x.w;
      float q = x.x*x.x + x.y*x.y + x.z*x.z + x.w*x.w;
      #pragma unroll
      for (int m = 32; m >= 1; m >>= 1){
        s += __shfl_xor(s, m, 64);
        q += __shfl_xor(q, m, 64);
      }
      const float mu  = s * (1.f/256.f);
      const float var = q * (1.f/256.f) - mu*mu;
      const float rs  = rsqrtf(var + 1e-5f);
      const float4 g  = *(const float4*)(gamma + lane*4);
      const float4 bb = *(const float4*)(beta  + lane*4);
      us4 v;
      v[0] = f2bf((x.x - mu)*rs*g.x + bb.x);
      v[1] = f2bf((x.y - mu)*rs*g.y + bb.y);
      v[2] = f2bf((x.z - mu)*rs*g.z + bb.z);
      v[3] = f2bf((x.w - mu)*rs*g.w + bb.w);
      *(us4*)&s_ctil[r*520 + lane*4] = v;          // agg region, dead after C
    }
  }
  // no barrier: ctx_n rows wave-local

  // ---- Phase E: out-right = ctx_n @ Wx^T; 4 rows/thread, vectorized reads ----
  {
    f32x4 eacc[4];
    #pragma unroll
    for (int rr = 0; rr < 4; ++rr) eacc[rr] = (f32x4){0,0,0,0};
    #pragma unroll 1
    for (int k0 = 0; k0 < 256; k0 += 8){
      us8 a8[4];
      #pragma unroll
      for (int rr = 0; rr < 4; ++rr)
        a8[rr] = *(const us8*)&s_ctil[(4*rt+rr)*520 + k0];
      #pragma unroll
      for (int kk = 0; kk < 8; ++kk){
        const f32x4 w = *((const f32x4*)(W3T + ((k0+kk) << 7)) + ct);
        #pragma unroll
        for (int rr = 0; rr < 4; ++rr) eacc[rr] += bf2f(a8[rr][kk]) * w;
      }
    }
    #pragma unroll
    for (int rr = 0; rr < 4; ++rr)
      *(f32x4*)&out[((long)(b0 + 4*rt + rr) << 8) + 128 + ct*4] = eacc[rr];
  }
}

extern "C" void kernel_launch(void* const* d_in, const int* in_sizes, int n_in,
                              void* d_out, int out_size, void* d_ws, size_t ws_size,
                              hipStream_t stream){
  const float* center = (const float*)d_in[0];
  const float* nbr    = (const float*)d_in[1];
  const float* ew     = (const float*)d_in[2];
  const float* Wq     = (const float*)d_in[3];
  const float* Wk     = (const float*)d_in[4];
  const float* Wv     = (const float*)d_in[5];
  const float* Wc     = (const float*)d_in[6];
  const float* Wx     = (const float*)d_in[7];
  const float* gamma  = (const float*)d_in[8];
  const float* beta   = (const float*)d_in[9];
  (void)in_sizes; (void)n_in; (void)out_size;

  float* W = (float*)d_ws;   // exactly 1 MiB of workspace
  (void)ws_size;

  prep_kernel<<<1024, 256, 0, stream>>>(Wq, Wk, Wv, Wc, Wx, W);
  fused_kernel<<<Bsz/BR, 256, 0, stream>>>(center, nbr, ew, gamma, beta, W, (float*)d_out);
}

// Round 11
// 428.235 us; speedup vs baseline: 3.9339x; 1.0576x over previous
//
#include <hip/hip_runtime.h>

// B=32768, K=16, D=256, H=2, HD=128
#define Bsz 32768
#define BR  32           // rows per block; 8 rows per wave, wave-autonomous
#define SCALE 0.08838834764831845f   // 1/sqrt(128)

typedef __attribute__((ext_vector_type(4))) float f32x4;
typedef __attribute__((ext_vector_type(4))) unsigned short us4;
typedef __attribute__((ext_vector_type(8))) unsigned short us8;

static __device__ __forceinline__ unsigned short f2bf(float x){
  unsigned int u = __builtin_bit_cast(unsigned int, x);
  u += 0x7FFFu + ((u >> 16) & 1u);          // RNE
  return (unsigned short)(u >> 16);
}
static __device__ __forceinline__ float bf2f(unsigned short h){
  unsigned int u = ((unsigned int)h) << 16;
  return __builtin_bit_cast(float, u);
}

// ---------------------------------------------------------------------------
// Prep (identical to passing rounds 5-10): fp32 weights, k-major.
//   W1T f32 [256][640]: n<512 -> M_h[k][m] (m=n&255,h=n>>8); 512..639 -> Wc
//   W2T f32 [256][256]: Wv transposed;  W3T f32 [256][128]: Wx transposed
// ---------------------------------------------------------------------------
__global__ void prep_kernel(const float* __restrict__ Wq, const float* __restrict__ Wk,
                            const float* __restrict__ Wv, const float* __restrict__ Wc,
                            const float* __restrict__ Wx, float* __restrict__ wsf){
  float* W1T = wsf;                  // [256][640]
  float* W2T = wsf + 256*640;        // [256][256]
  float* W3T = W2T + 256*256;        // [256][128]
  const int n = blockIdx.x;
  const int k = threadIdx.x;
  if (n < 512){
    const int h = n >> 8, m = n & 255;
    const float* wq = Wq + h*128*256 + k;
    const float* wk = Wk + h*128*256 + m;
    float s = 0.f;
    for (int d = 0; d < 128; ++d) s += wq[d*256] * wk[d*256];
    W1T[k*640 + n] = s;
  } else if (n < 640){
    W1T[k*640 + n] = Wc[(n-512)*256 + k];
  } else if (n < 896){
    const int r = n - 640;
    W2T[k*256 + r] = Wv[r*256 + k];
  } else {
    const int r = n - 896;
    W3T[k*128 + r] = Wx[r*256 + k];
  }
}

// ---------------------------------------------------------------------------
// Fused kernel, BR=32, 256 threads (4 waves), ZERO BARRIERS (wave w owns rows
// 8w..8w+7 through all phases; all LDS traffic wave-local; lockstep WAR only).
// Changes vs round 10 (latency/occupancy round):
//  - no center staging: phase A streams center fp32 from global (broadcast
//    addresses) with 1-iteration-ahead register prefetch
//  - phase A split into 2 k-passes (acc 48/32 VGPR) for load-hoisting room
//  - ctx + LayerNorm fully in registers (ct-lane shfl reduce); phase D gone
//  - single LDS buffer s_ctil [32][520] bf16 (33.3 KB -> 4 blocks/CU):
//      ctil (A..B) -> wbuf overlay (B) -> agg overlay (B..C) -> ctx_n (C..E)
//  - __launch_bounds__(256,4): 128-VGPR cap
// Thread map in A/C/E: rt=tid>>5 (rows 4rt..4rt+3), ct=tid&31 (col quads).
// ---------------------------------------------------------------------------
__global__ __launch_bounds__(256, 4) void fused_kernel(
    const float* __restrict__ center, const float* __restrict__ nbr,
    const float* __restrict__ ew, const float* __restrict__ gamma,
    const float* __restrict__ beta, const float* __restrict__ Wall,
    float* __restrict__ out)
{
  __shared__ __align__(16) unsigned short s_ctil[BR*520];

  const int tid  = threadIdx.x;
  const int wid  = tid >> 6;
  const int lane = tid & 63;
  const int b0   = blockIdx.x * BR;

  const float* W1T = Wall;               // [256][640]
  const float* W2T = Wall + 256*640;     // [256][256]
  const float* W3T = W2T + 256*256;      // [256][128]

  const int rt = tid >> 5;     // 0..7  (rows 4rt..4rt+3)
  const int ct = tid & 31;     // 0..31 (col quad)

  // ---- Phase A pass 1: tiles {0,1,4} -> ctil cols 0..255 + out-left ----
  {
    f32x4 acc[4][3];
    #pragma unroll
    for (int rr = 0; rr < 4; ++rr)
      #pragma unroll
      for (int t = 0; t < 3; ++t) acc[rr][t] = (f32x4){0,0,0,0};
    float4 aP[4];
    #pragma unroll
    for (int rr = 0; rr < 4; ++rr)
      aP[rr] = *(const float4*)(center + ((long)(b0 + 4*rt + rr) << 8));
    #pragma unroll 1
    for (int k0 = 0; k0 < 256; k0 += 4){
      float4 aC[4];
      #pragma unroll
      for (int rr = 0; rr < 4; ++rr) aC[rr] = aP[rr];
      const int kn = (k0 + 4) & 255;     // wraps harmlessly on last iter
      #pragma unroll
      for (int rr = 0; rr < 4; ++rr)
        aP[rr] = *(const float4*)(center + ((long)(b0 + 4*rt + rr) << 8) + kn);
      #pragma unroll
      for (int kk = 0; kk < 4; ++kk){
        const float* wrow = W1T + (k0+kk)*640;
        const f32x4 w0 = ((const f32x4*)(wrow      ))[ct];
        const f32x4 w1 = ((const f32x4*)(wrow + 128))[ct];
        const f32x4 w4 = ((const f32x4*)(wrow + 512))[ct];
        #pragma unroll
        for (int rr = 0; rr < 4; ++rr){
          const float a = aC[rr][kk];
          acc[rr][0] += a * w0;
          acc[rr][1] += a * w1;
          acc[rr][2] += a * w4;
        }
      }
    }
    #pragma unroll
    for (int rr = 0; rr < 4; ++rr){
      const int r = 4*rt + rr;
      us4 v0, v1;
      #pragma unroll
      for (int j = 0; j < 4; ++j){ v0[j] = f2bf(acc[rr][0][j]); v1[j] = f2bf(acc[rr][1][j]); }
      *(us4*)&s_ctil[r*520 + ct*4]       = v0;
      *(us4*)&s_ctil[r*520 + 128 + ct*4] = v1;
      *(f32x4*)&out[((long)(b0 + r) << 8) + ct*4] = acc[rr][2];
    }
  }

  // ---- Phase A pass 2: tiles {2,3} -> ctil cols 256..511 ----
  {
    f32x4 acc[4][2];
    #pragma unroll
    for (int rr = 0; rr < 4; ++rr){ acc[rr][0] = (f32x4){0,0,0,0}; acc[rr][1] = (f32x4){0,0,0,0}; }
    float4 aP[4];
    #pragma unroll
    for (int rr = 0; rr < 4; ++rr)
      aP[rr] = *(const float4*)(center + ((long)(b0 + 4*rt + rr) << 8));
    #pragma unroll 1
    for (int k0 = 0; k0 < 256; k0 += 4){
      float4 aC[4];
      #pragma unroll
      for (int rr = 0; rr < 4; ++rr) aC[rr] = aP[rr];
      const int kn = (k0 + 4) & 255;
      #pragma unroll
      for (int rr = 0; rr < 4; ++rr)
        aP[rr] = *(const float4*)(center + ((long)(b0 + 4*rt + rr) << 8) + kn);
      #pragma unroll
      for (int kk = 0; kk < 4; ++kk){
        const float* wrow = W1T + (k0+kk)*640;
        const f32x4 w2 = ((const f32x4*)(wrow + 256))[ct];
        const f32x4 w3 = ((const f32x4*)(wrow + 384))[ct];
        #pragma unroll
        for (int rr = 0; rr < 4; ++rr){
          const float a = aC[rr][kk];
          acc[rr][0] += a * w2;
          acc[rr][1] += a * w3;
        }
      }
    }
    #pragma unroll
    for (int rr = 0; rr < 4; ++rr){
      const int r = 4*rt + rr;
      us4 v0, v1;
      #pragma unroll
      for (int j = 0; j < 4; ++j){ v0[j] = f2bf(acc[rr][0][j]); v1[j] = f2bf(acc[rr][1][j]); }
      *(us4*)&s_ctil[r*520 + 256 + ct*4] = v0;
      *(us4*)&s_ctil[r*520 + 384 + ct*4] = v1;
    }
  }
  // no barrier: ctil rows wave-local

  // ---- Phase B: attention, 8 rows/wave; reduce-scatter scores ----
  {
    const int myk = ((lane>>4)&1)*8 + ((lane>>3)&1)*4 + ((lane>>2)&1)*2 + ((lane>>1)&1);
    const int myh = lane >> 5;
    #pragma unroll 1
    for (int rr = 0; rr < 8; ++rr){
      const int r = wid*8 + rr;
      const long b = b0 + r;
      float4 c0, c1;
      {
        us4 h0 = *(const us4*)&s_ctil[r*520 + lane*4];
        us4 h1 = *(const us4*)&s_ctil[r*520 + 256 + lane*4];
        c0.x=bf2f(h0[0]); c0.y=bf2f(h0[1]); c0.z=bf2f(h0[2]); c0.w=bf2f(h0[3]);
        c1.x=bf2f(h1[0]); c1.y=bf2f(h1[1]); c1.z=bf2f(h1[2]); c1.w=bf2f(h1[3]);
      }
      float4 xv[16];
      const float* npt = nbr + ((b << 4) << 8) + lane*4;
      #pragma unroll
      for (int k = 0; k < 16; ++k) xv[k] = *(const float4*)(npt + (k << 8));
      float P0[16], P1[16];
      #pragma unroll
      for (int k = 0; k < 16; ++k){
        P0[k] = xv[k].x*c0.x + xv[k].y*c0.y + xv[k].z*c0.z + xv[k].w*c0.w;
        P1[k] = xv[k].x*c1.x + xv[k].y*c1.y + xv[k].z*c1.z + xv[k].w*c1.w;
      }
      // reduce-scatter: masks 32,16,8,4,2, then final 1
      const int b5 = lane & 32, b4 = lane & 16, b3 = lane & 8, b2 = lane & 4, b1 = lane & 2;
      float Q[16];
      #pragma unroll
      for (int j = 0; j < 16; ++j){
        const float give = b5 ? P0[j] : P1[j];
        const float keep = b5 ? P1[j] : P0[j];
        Q[j] = keep + __shfl_xor(give, 32, 64);
      }
      float R[8];
      #pragma unroll
      for (int j = 0; j < 8; ++j){
        const float give = b4 ? Q[j] : Q[8+j];
        const float keep = b4 ? Q[8+j] : Q[j];
        R[j] = keep + __shfl_xor(give, 16, 64);
      }
      float S[4];
      #pragma unroll
      for (int j = 0; j < 4; ++j){
        const float give = b3 ? R[j] : R[4+j];
        const float keep = b3 ? R[4+j] : R[j];
        S[j] = keep + __shfl_xor(give, 8, 64);
      }
      float T[2];
      #pragma unroll
      for (int j = 0; j < 2; ++j){
        const float give = b2 ? S[j] : S[2+j];
        const float keep = b2 ? S[2+j] : S[j];
        T[j] = keep + __shfl_xor(give, 4, 64);
      }
      float U;
      {
        const float give = b1 ? T[0] : T[1];
        const float keep = b1 ? T[1] : T[0];
        U = keep + __shfl_xor(give, 2, 64);
      }
      const float sfull = U + __shfl_xor(U, 1, 64);   // s[myh][myk]
      const float erk = ew[b*16 + myk];
      const float e = __expf(sfull*SCALE + erk);      // scores O(1): no max-sub
      float dn = e;
      dn += __shfl_xor(dn, 2, 64);
      dn += __shfl_xor(dn, 4, 64);
      dn += __shfl_xor(dn, 8, 64);
      dn += __shfl_xor(dn, 16, 64);
      const float w = e / dn;
      // broadcast via wave-local LDS overlay of head1-ctil cells (c1 already read)
      float* wbuf = (float*)&s_ctil[r*520 + 256];
      wbuf[myh*16 + myk] = w;                         // 2 lanes same addr, same value
      f32x4 wv[8];
      #pragma unroll
      for (int t = 0; t < 8; ++t) wv[t] = ((const f32x4*)wbuf)[t];
      float4 agg0 = {0,0,0,0}, agg1 = {0,0,0,0};
      #pragma unroll
      for (int k = 0; k < 16; ++k){
        const float w0 = wv[k>>2][k&3];
        const float w1 = wv[4 + (k>>2)][k&3];
        agg0.x += w0*xv[k].x; agg0.y += w0*xv[k].y; agg0.z += w0*xv[k].z; agg0.w += w0*xv[k].w;
        agg1.x += w1*xv[k].x; agg1.y += w1*xv[k].y; agg1.z += w1*xv[k].z; agg1.w += w1*xv[k].w;
      }
      us4 v0, v1;
      v0[0]=f2bf(agg0.x); v0[1]=f2bf(agg0.y); v0[2]=f2bf(agg0.z); v0[3]=f2bf(agg0.w);
      v1[0]=f2bf(agg1.x); v1[1]=f2bf(agg1.y); v1[2]=f2bf(agg1.z); v1[3]=f2bf(agg1.w);
      *(us4*)&s_ctil[r*520 + lane*4]       = v0;   // agg overlays ctil (WAR, lockstep)
      *(us4*)&s_ctil[r*520 + 256 + lane*4] = v1;   // overwrites wbuf after wv read
    }
  }
  // no barrier: agg rows wave-local

  // ---- Phase C (+fused LayerNorm): ctx in registers, ctx_n bf16 -> LDS ----
  {
    f32x4 cacc[4][2];
    #pragma unroll
    for (int rr = 0; rr < 4; ++rr){ cacc[rr][0] = (f32x4){0,0,0,0}; cacc[rr][1] = (f32x4){0,0,0,0}; }
    #pragma unroll 1
    for (int k0 = 0; k0 < 256; k0 += 8){
      us8 a0[4], a1[4];
      #pragma unroll
      for (int rr = 0; rr < 4; ++rr){
        a0[rr] = *(const us8*)&s_ctil[(4*rt+rr)*520 + k0];
        a1[rr] = *(const us8*)&s_ctil[(4*rt+rr)*520 + 256 + k0];
      }
      #pragma unroll
      for (int kk = 0; kk < 8; ++kk){
        const float* wrow = W2T + ((k0+kk) << 8);
        const f32x4 w0 = ((const f32x4*)(wrow      ))[ct];   // cols 0..127  (head0)
        const f32x4 w1 = ((const f32x4*)(wrow + 128))[ct];   // cols 128..255 (head1)
        #pragma unroll
        for (int rr = 0; rr < 4; ++rr){
          cacc[rr][0] += bf2f(a0[rr][kk]) * w0;
          cacc[rr][1] += bf2f(a1[rr][kk]) * w1;
        }
      }
    }
    // fused LayerNorm over the 32 ct-lanes sharing this rt (lane bits 0..4)
    const f32x4 gv0 = ((const f32x4*)gamma)[ct],      gv1 = ((const f32x4*)gamma)[32 + ct];
    const f32x4 bv0 = ((const f32x4*)beta )[ct],      bv1 = ((const f32x4*)beta )[32 + ct];
    #pragma unroll
    for (int rr = 0; rr < 4; ++rr){
      float s = 0.f, q = 0.f;
      #pragma unroll
      for (int t = 0; t < 2; ++t)
        #pragma unroll
        for (int j = 0; j < 4; ++j){
          const float x = cacc[rr][t][j];
          s += x; q += x*x;
        }
      #pragma unroll
      for (int m = 16; m >= 1; m >>= 1){
        s += __shfl_xor(s, m, 64);
        q += __shfl_xor(q, m, 64);
      }
      const float mu  = s * (1.f/256.f);
      const float var = q * (1.f/256.f) - mu*mu;
      const float rs  = rsqrtf(var + 1e-5f);
      const int r = 4*rt + rr;
      us4 v0, v1;
      #pragma unroll
      for (int j = 0; j < 4; ++j){
        v0[j] = f2bf((cacc[rr][0][j] - mu)*rs*gv0[j] + bv0[j]);
        v1[j] = f2bf((cacc[rr][1][j] - mu)*rs*gv1[j] + bv1[j]);
      }
      *(us4*)&s_ctil[r*520 + ct*4]       = v0;   // ctx_n cols 0..127 (lockstep WAR)
      *(us4*)&s_ctil[r*520 + 128 + ct*4] = v1;   // ctx_n cols 128..255
    }
  }
  // no barrier: ctx_n rows wave-local

  // ---- Phase E: out-right = ctx_n @ Wx^T ----
  {
    f32x4 eacc[4];
    #pragma unroll
    for (int rr = 0; rr < 4; ++rr) eacc[rr] = (f32x4){0,0,0,0};
    #pragma unroll 1
    for (int k0 = 0; k0 < 256; k0 += 8){
      us8 a[4];
      #pragma unroll
      for (int rr = 0; rr < 4; ++rr)
        a[rr] = *(const us8*)&s_ctil[(4*rt+rr)*520 + k0];
      #pragma unroll
      for (int kk = 0; kk < 8; ++kk){
        const f32x4 w = ((const f32x4*)(W3T + ((k0+kk) << 7)))[ct];
        #pragma unroll
        for (int rr = 0; rr < 4; ++rr) eacc[rr] += bf2f(a[rr][kk]) * w;
      }
    }
    #pragma unroll
    for (int rr = 0; rr < 4; ++rr)
      *(f32x4*)&out[((long)(b0 + 4*rt + rr) << 8) + 128 + ct*4] = eacc[rr];
  }
}

extern "C" void kernel_launch(void* const* d_in, const int* in_sizes, int n_in,
                              void* d_out, int out_size, void* d_ws, size_t ws_size,
                              hipStream_t stream){
  const float* center = (const float*)d_in[0];
  const float* nbr    = (const float*)d_in[1];
  const float* ew     = (const float*)d_in[2];
  const float* Wq     = (const float*)d_in[3];
  const float* Wk     = (const float*)d_in[4];
  const float* Wv     = (const float*)d_in[5];
  const float* Wc     = (const float*)d_in[6];
  const float* Wx     = (const float*)d_in[7];
  const float* gamma  = (const float*)d_in[8];
  const float* beta   = (const float*)d_in[9];
  (void)in_sizes; (void)n_in; (void)out_size;

  float* W = (float*)d_ws;   // exactly 1 MiB of workspace
  (void)ws_size;

  prep_kernel<<<1024, 256, 0, stream>>>(Wq, Wk, Wv, Wc, Wx, W);
  fused_kernel<<<Bsz/BR, 256, 0, stream>>>(center, nbr, ew, gamma, beta, W, (float*)d_out);
}

// Round 12
// 254.177 us; speedup vs baseline: 6.6278x; 1.6848x over previous
//
#include <hip/hip_runtime.h>

// B=32768, K=16, D=256, H=2, HD=128
#define Bsz 32768
#define BR  32           // rows per block; 8 rows per wave, wave-autonomous
#define SCALE 0.08838834764831845f   // 1/sqrt(128)

typedef __attribute__((ext_vector_type(4))) float f32x4;
typedef __attribute__((ext_vector_type(4))) unsigned short us4;
typedef __attribute__((ext_vector_type(4))) unsigned int ui4;
typedef __attribute__((ext_vector_type(2))) unsigned int ui2;
typedef _Float16 __attribute__((ext_vector_type(2))) h2;

static __device__ __forceinline__ unsigned int pk16(float a, float b){
  return __builtin_bit_cast(unsigned int, __builtin_amdgcn_cvt_pkrtz(a, b));
}
static __device__ __forceinline__ h2 uph(unsigned int u){
  return __builtin_bit_cast(h2, u);
}
static __device__ __forceinline__ float h2f(unsigned short h){
  return (float)__builtin_bit_cast(_Float16, h);
}
#define FDOT2(a, b, c) __builtin_amdgcn_fdot2((a), (b), (c), false)

// ---------------------------------------------------------------------------
// Prep: f16 k-PAIR-packed weights (uint = 2 f16 for k=2kp,2kp+1), k-major.
//   W1P uint [128][640]: cols 0..511 -> M_h[k][m] (h=n>>8,m=n&255); 512..639 Wc
//   W2P uint [128][256]: Wv^T packed;  W3P uint [128][128]: Wx^T packed
// Total 512 KiB. Pack via shfl_xor(val,1) + v_cvt_pkrtz (even lanes store).
// ---------------------------------------------------------------------------
__global__ void prep_kernel(const float* __restrict__ Wq, const float* __restrict__ Wk,
                            const float* __restrict__ Wv, const float* __restrict__ Wc,
                            const float* __restrict__ Wx, unsigned int* __restrict__ wsp){
  unsigned int* W1P = wsp;                 // [128][640]
  unsigned int* W2P = wsp + 128*640;       // [128][256]
  unsigned int* W3P = W2P + 128*256;       // [128][128]
  const int n = blockIdx.x;
  const int k = threadIdx.x;
  float val;
  if (n < 512){
    const int h = n >> 8, m = n & 255;
    const float* wq = Wq + h*128*256 + k;
    const float* wk = Wk + h*128*256 + m;
    float s = 0.f;
    for (int d = 0; d < 128; ++d) s += wq[d*256] * wk[d*256];
    val = s;
  } else if (n < 640){
    val = Wc[(n-512)*256 + k];
  } else if (n < 896){
    val = Wv[(n-640)*256 + k];
  } else {
    val = Wx[(n-896)*256 + k];
  }
  const float vo = __shfl_xor(val, 1, 64);
  if ((k & 1) == 0){
    const unsigned int p = pk16(val, vo);
    const int kp = k >> 1;
    if (n < 640)      W1P[kp*640 + n] = p;
    else if (n < 896) W2P[kp*256 + (n-640)] = p;
    else              W3P[kp*128 + (n-896)] = p;
  }
}

// ---------------------------------------------------------------------------
// Fused kernel, BR=32, 256 threads (4 waves), ZERO BARRIERS (wave w owns rows
// 8w..8w+7 in all phases; lockstep WAR overlays only). v_dot2_f32_f16 GEMMs.
// LDS: single s_ctil us[32][520] (33.3 KB -> 4 blocks/CU). Per-row cell map:
//   [256..511]: center packed f16 pairs (stage..A)    -> ctil cols 256..511
//               (pass2 post-loop) -> wbuf/agg1 (B) -> ctx_n? no:
//   [0..255]  : ctil cols 0..255 (A..B) -> agg0 (B..C) -> ctx_n (LN..E)
//   [256..511]: ctil cols 256..511 (A..B) -> wbuf+agg1 (B..C)
// Thread map A/C/E: rt=tid>>5 (rows 4rt..4rt+3), ct=tid&31 (col quads).
// ---------------------------------------------------------------------------
__global__ __launch_bounds__(256, 4) void fused_kernel(
    const float* __restrict__ center, const float* __restrict__ nbr,
    const float* __restrict__ ew, const float* __restrict__ gamma,
    const float* __restrict__ beta, const unsigned int* __restrict__ Wall,
    float* __restrict__ out)
{
  __shared__ __align__(16) unsigned short s_ctil[BR*520];

  const int tid  = threadIdx.x;
  const int wid  = tid >> 6;
  const int lane = tid & 63;
  const int b0   = blockIdx.x * BR;

  const unsigned int* W1P = Wall;               // [128][640]
  const unsigned int* W2P = Wall + 128*640;     // [128][256]
  const unsigned int* W3P = W2P + 128*256;      // [128][128]

  const int rt = tid >> 5;     // 0..7  (rows 4rt..4rt+3)
  const int ct = tid & 31;     // 0..31 (col quad)

  // ---- stage center rows 8w..8w+7 as packed f16 pairs -> cells 256..511 ----
  {
    const int sr = tid >> 3;            // 0..31, wave-local rows
    const int fc = (tid & 7) * 32;      // float col base
    const float* cp = center + ((long)(b0 + sr) << 8) + fc;
    #pragma unroll
    for (int it = 0; it < 4; ++it){
      float4 a = *(const float4*)(cp + it*8);
      float4 b = *(const float4*)(cp + it*8 + 4);
      ui4 v = {pk16(a.x,a.y), pk16(a.z,a.w), pk16(b.x,b.y), pk16(b.z,b.w)};
      *(ui4*)&s_ctil[sr*520 + 256 + fc + it*8] = v;
    }
  }
  // no barrier: wave-local

  // ---- Phase A pass 1: tiles {0,1,4} -> ctil cols 0..255 + out-left ----
  {
    f32x4 acc[4][3];
    #pragma unroll
    for (int rr = 0; rr < 4; ++rr)
      #pragma unroll
      for (int t = 0; t < 3; ++t) acc[rr][t] = (f32x4){0,0,0,0};
    #pragma unroll 1
    for (int k0 = 0; k0 < 256; k0 += 8){
      ui4 a8[4];
      #pragma unroll
      for (int rr = 0; rr < 4; ++rr)
        a8[rr] = *(const ui4*)&s_ctil[(4*rt+rr)*520 + 256 + k0];
      #pragma unroll
      for (int kp = 0; kp < 4; ++kp){
        const unsigned int* wrow = W1P + ((k0>>1) + kp)*640;
        const ui4 w0 = ((const ui4*)(wrow      ))[ct];
        const ui4 w1 = ((const ui4*)(wrow + 128))[ct];
        const ui4 w4 = ((const ui4*)(wrow + 512))[ct];
        #pragma unroll
        for (int rr = 0; rr < 4; ++rr){
          const h2 a2 = uph(a8[rr][kp]);
          #pragma unroll
          for (int j = 0; j < 4; ++j){
            acc[rr][0][j] = FDOT2(a2, uph(w0[j]), acc[rr][0][j]);
            acc[rr][1][j] = FDOT2(a2, uph(w1[j]), acc[rr][1][j]);
            acc[rr][2][j] = FDOT2(a2, uph(w4[j]), acc[rr][2][j]);
          }
        }
      }
    }
    #pragma unroll
    for (int rr = 0; rr < 4; ++rr){
      const int r = 4*rt + rr;
      ui2 v0 = {pk16(acc[rr][0][0], acc[rr][0][1]), pk16(acc[rr][0][2], acc[rr][0][3])};
      ui2 v1 = {pk16(acc[rr][1][0], acc[rr][1][1]), pk16(acc[rr][1][2], acc[rr][1][3])};
      *(ui2*)&s_ctil[r*520 + ct*4]       = v0;    // ctil cols ct*4..+3
      *(ui2*)&s_ctil[r*520 + 128 + ct*4] = v1;    // ctil cols 128+..
      *(f32x4*)&out[((long)(b0 + r) << 8) + ct*4] = acc[rr][2];
    }
  }

  // ---- Phase A pass 2: tiles {2,3} -> ctil cols 256..511 (post-loop write) ----
  {
    f32x4 acc[4][2];
    #pragma unroll
    for (int rr = 0; rr < 4; ++rr){ acc[rr][0] = (f32x4){0,0,0,0}; acc[rr][1] = (f32x4){0,0,0,0}; }
    #pragma unroll 1
    for (int k0 = 0; k0 < 256; k0 += 8){
      ui4 a8[4];
      #pragma unroll
      for (int rr = 0; rr < 4; ++rr)
        a8[rr] = *(const ui4*)&s_ctil[(4*rt+rr)*520 + 256 + k0];
      #pragma unroll
      for (int kp = 0; kp < 4; ++kp){
        const unsigned int* wrow = W1P + ((k0>>1) + kp)*640;
        const ui4 w2 = ((const ui4*)(wrow + 256))[ct];
        const ui4 w3 = ((const ui4*)(wrow + 384))[ct];
        #pragma unroll
        for (int rr = 0; rr < 4; ++rr){
          const h2 a2 = uph(a8[rr][kp]);
          #pragma unroll
          for (int j = 0; j < 4; ++j){
            acc[rr][0][j] = FDOT2(a2, uph(w2[j]), acc[rr][0][j]);
            acc[rr][1][j] = FDOT2(a2, uph(w3[j]), acc[rr][1][j]);
          }
        }
      }
    }
    // all center reads done; safe to overwrite cells 256..511 (same wave)
    #pragma unroll
    for (int rr = 0; rr < 4; ++rr){
      const int r = 4*rt + rr;
      ui2 v0 = {pk16(acc[rr][0][0], acc[rr][0][1]), pk16(acc[rr][0][2], acc[rr][0][3])};
      ui2 v1 = {pk16(acc[rr][1][0], acc[rr][1][1]), pk16(acc[rr][1][2], acc[rr][1][3])};
      *(ui2*)&s_ctil[r*520 + 256 + ct*4] = v0;    // ctil cols 256+..
      *(ui2*)&s_ctil[r*520 + 384 + ct*4] = v1;    // ctil cols 384+..
    }
  }
  // no barrier: ctil rows wave-local

  // ---- Phase B: attention, 8 rows/wave; reduce-scatter scores ----
  {
    const int myk = ((lane>>4)&1)*8 + ((lane>>3)&1)*4 + ((lane>>2)&1)*2 + ((lane>>1)&1);
    const int myh = lane >> 5;
    #pragma unroll 1
    for (int rr = 0; rr < 8; ++rr){
      const int r = wid*8 + rr;
      const long b = b0 + r;
      float4 c0, c1;
      {
        us4 h0 = *(const us4*)&s_ctil[r*520 + lane*4];
        us4 h1 = *(const us4*)&s_ctil[r*520 + 256 + lane*4];
        c0.x=h2f(h0[0]); c0.y=h2f(h0[1]); c0.z=h2f(h0[2]); c0.w=h2f(h0[3]);
        c1.x=h2f(h1[0]); c1.y=h2f(h1[1]); c1.z=h2f(h1[2]); c1.w=h2f(h1[3]);
      }
      float4 xv[16];
      const float* npt = nbr + ((b << 4) << 8) + lane*4;
      #pragma unroll
      for (int k = 0; k < 16; ++k) xv[k] = *(const float4*)(npt + (k << 8));
      float P0[16], P1[16];
      #pragma unroll
      for (int k = 0; k < 16; ++k){
        P0[k] = xv[k].x*c0.x + xv[k].y*c0.y + xv[k].z*c0.z + xv[k].w*c0.w;
        P1[k] = xv[k].x*c1.x + xv[k].y*c1.y + xv[k].z*c1.z + xv[k].w*c1.w;
      }
      // reduce-scatter: masks 32,16,8,4,2, then final 1
      const int b5 = lane & 32, b4 = lane & 16, b3 = lane & 8, b2 = lane & 4, b1 = lane & 2;
      float Q[16];
      #pragma unroll
      for (int j = 0; j < 16; ++j){
        const float give = b5 ? P0[j] : P1[j];
        const float keep = b5 ? P1[j] : P0[j];
        Q[j] = keep + __shfl_xor(give, 32, 64);
      }
      float R[8];
      #pragma unroll
      for (int j = 0; j < 8; ++j){
        const float give = b4 ? Q[j] : Q[8+j];
        const float keep = b4 ? Q[8+j] : Q[j];
        R[j] = keep + __shfl_xor(give, 16, 64);
      }
      float S[4];
      #pragma unroll
      for (int j = 0; j < 4; ++j){
        const float give = b3 ? R[j] : R[4+j];
        const float keep = b3 ? R[4+j] : R[j];
        S[j] = keep + __shfl_xor(give, 8, 64);
      }
      float T[2];
      #pragma unroll
      for (int j = 0; j < 2; ++j){
        const float give = b2 ? S[j] : S[2+j];
        const float keep = b2 ? S[2+j] : S[j];
        T[j] = keep + __shfl_xor(give, 4, 64);
      }
      float U;
      {
        const float give = b1 ? T[0] : T[1];
        const float keep = b1 ? T[1] : T[0];
        U = keep + __shfl_xor(give, 2, 64);
      }
      const float sfull = U + __shfl_xor(U, 1, 64);   // s[myh][myk]
      const float erk = ew[b*16 + myk];
      const float e = __expf(sfull*SCALE + erk);      // scores O(1): no max-sub
      float dn = e;
      dn += __shfl_xor(dn, 2, 64);
      dn += __shfl_xor(dn, 4, 64);
      dn += __shfl_xor(dn, 8, 64);
      dn += __shfl_xor(dn, 16, 64);
      const float w = e / dn;
      // broadcast via wave-local overlay of head1-ctil cells (c1 already read)
      float* wbuf = (float*)&s_ctil[r*520 + 256];
      wbuf[myh*16 + myk] = w;                         // 2 lanes same addr, same value
      f32x4 wv[8];
      #pragma unroll
      for (int t = 0; t < 8; ++t) wv[t] = ((const f32x4*)wbuf)[t];
      float4 agg0 = {0,0,0,0}, agg1 = {0,0,0,0};
      #pragma unroll
      for (int k = 0; k < 16; ++k){
        const float w0 = wv[k>>2][k&3];
        const float w1 = wv[4 + (k>>2)][k&3];
        agg0.x += w0*xv[k].x; agg0.y += w0*xv[k].y; agg0.z += w0*xv[k].z; agg0.w += w0*xv[k].w;
        agg1.x += w1*xv[k].x; agg1.y += w1*xv[k].y; agg1.z += w1*xv[k].z; agg1.w += w1*xv[k].w;
      }
      ui2 v0 = {pk16(agg0.x, agg0.y), pk16(agg0.z, agg0.w)};
      ui2 v1 = {pk16(agg1.x, agg1.y), pk16(agg1.z, agg1.w)};
      *(ui2*)&s_ctil[r*520 + lane*4]       = v0;   // agg0 (WAR on own cells)
      *(ui2*)&s_ctil[r*520 + 256 + lane*4] = v1;   // agg1 (overwrites wbuf after read)
    }
  }
  // no barrier: agg rows wave-local

  // ---- Phase C (+fused LayerNorm): ctx in registers -> ctx_n packed f16 ----
  {
    f32x4 cacc[4][2];
    #pragma unroll
    for (int rr = 0; rr < 4; ++rr){ cacc[rr][0] = (f32x4){0,0,0,0}; cacc[rr][1] = (f32x4){0,0,0,0}; }
    #pragma unroll 1
    for (int k0 = 0; k0 < 256; k0 += 8){
      ui4 a0[4], a1[4];
      #pragma unroll
      for (int rr = 0; rr < 4; ++rr){
        a0[rr] = *(const ui4*)&s_ctil[(4*rt+rr)*520 + k0];
        a1[rr] = *(const ui4*)&s_ctil[(4*rt+rr)*520 + 256 + k0];
      }
      #pragma unroll
      for (int kp = 0; kp < 4; ++kp){
        const unsigned int* wrow = W2P + ((k0>>1) + kp)*256;
        const ui4 w0 = ((const ui4*)(wrow      ))[ct];   // ctx cols 0..127 (head0)
        const ui4 w1 = ((const ui4*)(wrow + 128))[ct];   // ctx cols 128..255 (head1)
        #pragma unroll
        for (int rr = 0; rr < 4; ++rr){
          const h2 x0 = uph(a0[rr][kp]);
          const h2 x1 = uph(a1[rr][kp]);
          #pragma unroll
          for (int j = 0; j < 4; ++j){
            cacc[rr][0][j] = FDOT2(x0, uph(w0[j]), cacc[rr][0][j]);
            cacc[rr][1][j] = FDOT2(x1, uph(w1[j]), cacc[rr][1][j]);
          }
        }
      }
    }
    // fused LayerNorm across the 32 ct-lanes of each rt group
    const f32x4 gv0 = ((const f32x4*)gamma)[ct], gv1 = ((const f32x4*)gamma)[32 + ct];
    const f32x4 bv0 = ((const f32x4*)beta )[ct], bv1 = ((const f32x4*)beta )[32 + ct];
    #pragma unroll
    for (int rr = 0; rr < 4; ++rr){
      float s = 0.f, q = 0.f;
      #pragma unroll
      for (int t = 0; t < 2; ++t)
        #pragma unroll
        for (int j = 0; j < 4; ++j){
          const float x = cacc[rr][t][j];
          s += x; q += x*x;
        }
      #pragma unroll
      for (int m = 16; m >= 1; m >>= 1){
        s += __shfl_xor(s, m, 64);
        q += __shfl_xor(q, m, 64);
      }
      const float mu  = s * (1.f/256.f);
      const float var = q * (1.f/256.f) - mu*mu;
      const float rs  = rsqrtf(var + 1e-5f);
      const int r = 4*rt + rr;
      float y0[4], y1[4];
      #pragma unroll
      for (int j = 0; j < 4; ++j){
        y0[j] = (cacc[rr][0][j] - mu)*rs*gv0[j] + bv0[j];
        y1[j] = (cacc[rr][1][j] - mu)*rs*gv1[j] + bv1[j];
      }
      ui2 v0 = {pk16(y0[0], y0[1]), pk16(y0[2], y0[3])};
      ui2 v1 = {pk16(y1[0], y1[1]), pk16(y1[2], y1[3])};
      *(ui2*)&s_ctil[r*520 + ct*4]       = v0;   // ctx_n cols ct*4..+3
      *(ui2*)&s_ctil[r*520 + 128 + ct*4] = v1;   // ctx_n cols 128+..
    }
  }
  // no barrier: ctx_n rows wave-local

  // ---- Phase E: out-right = ctx_n @ Wx^T ----
  {
    f32x4 eacc[4];
    #pragma unroll
    for (int rr = 0; rr < 4; ++rr) eacc[rr] = (f32x4){0,0,0,0};
    #pragma unroll 1
    for (int k0 = 0; k0 < 256; k0 += 8){
      ui4 a[4];
      #pragma unroll
      for (int rr = 0; rr < 4; ++rr)
        a[rr] = *(const ui4*)&s_ctil[(4*rt+rr)*520 + k0];
      #pragma unroll
      for (int kp = 0; kp < 4; ++kp){
        const ui4 w = ((const ui4*)(W3P + ((k0>>1) + kp)*128))[ct];
        #pragma unroll
        for (int rr = 0; rr < 4; ++rr){
          const h2 x = uph(a[rr][kp]);
          #pragma unroll
          for (int j = 0; j < 4; ++j)
            eacc[rr][j] = FDOT2(x, uph(w[j]), eacc[rr][j]);
        }
      }
    }
    #pragma unroll
    for (int rr = 0; rr < 4; ++rr)
      *(f32x4*)&out[((long)(b0 + 4*rt + rr) << 8) + 128 + ct*4] = eacc[rr];
  }
}

extern "C" void kernel_launch(void* const* d_in, const int* in_sizes, int n_in,
                              void* d_out, int out_size, void* d_ws, size_t ws_size,
                              hipStream_t stream){
  const float* center = (const float*)d_in[0];
  const float* nbr    = (const float*)d_in[1];
  const float* ew     = (const float*)d_in[2];
  const float* Wq     = (const float*)d_in[3];
  const float* Wk     = (const float*)d_in[4];
  const float* Wv     = (const float*)d_in[5];
  const float* Wc     = (const float*)d_in[6];
  const float* Wx     = (const float*)d_in[7];
  const float* gamma  = (const float*)d_in[8];
  const float* beta   = (const float*)d_in[9];
  (void)in_sizes; (void)n_in; (void)out_size;

  unsigned int* W = (unsigned int*)d_ws;   // 512 KiB of workspace
  (void)ws_size;

  prep_kernel<<<1024, 256, 0, stream>>>(Wq, Wk, Wv, Wc, Wx, W);
  fused_kernel<<<Bsz/BR, 256, 0, stream>>>(center, nbr, ew, gamma, beta, W, (float*)d_out);
}